// Round 1
// baseline (2622.288 us; speedup 1.0000x reference)
//
#include <hip/hip_runtime.h>

typedef float f4 __attribute__((ext_vector_type(4)));

#define BM 64
#define BN 64
#define BK 16

enum { MODE_NT = 0, MODE_TN = 1, MODE_CTX = 2 };

// C[m,n] = alpha * sum_k A(m,k)*B(n,k), batched over blockIdx.z.
// NT : A(m,k)=A[m*lda+k]        B(n,k)=B[n*ldb+k]
// TN : A(m,k)=A[k*lda+m]        B(n,k)=B[k*ldb+n]
// CTX: k=(h,j), h=k/960, j=k%960
//      A(m,k)=A[h*hA + m*960 + j]   B(n,k)=B[h*hB + n*960 + j]
template<int MODE>
__global__ __launch_bounds__(256)
void gemm_k(const float* __restrict__ Ag, const float* __restrict__ Bg,
            float* __restrict__ Cg,
            int M, int N, int K, int lda, int ldb, int ldc,
            int divA, long long sAhi, long long sAlo,
            int divB, long long sBhi, long long sBlo,
            long long sC, long long hA, long long hB, float alpha)
{
    const int z = blockIdx.z;
    const float* A = Ag + (long long)(z / divA) * sAhi + (long long)(z % divA) * sAlo;
    const float* B = Bg + (long long)(z / divB) * sBhi + (long long)(z % divB) * sBlo;
    float* C = Cg + (long long)z * sC;

    __shared__ float As[BK][BM + 4];
    __shared__ float Bs[BK][BN + 4];

    const int tid = threadIdx.x;
    const int m0 = blockIdx.x * BM, n0 = blockIdx.y * BN;
    const int ty = tid >> 4, tx = tid & 15;

    float acc[4][4] = {};

    const int Kt = (K + BK - 1) / BK;
    for (int kt = 0; kt < Kt; ++kt) {
        const int k0 = kt * BK;
        if (MODE == MODE_NT) {
            const int m = tid >> 2, kq = tid & 3;
            const int gm = m0 + m, gk = k0 + kq * 4;
            f4 av = {0.f, 0.f, 0.f, 0.f};
            if (gm < M && gk < K) av = *(const f4*)&A[(long long)gm * lda + gk];
            As[kq * 4 + 0][m] = av[0]; As[kq * 4 + 1][m] = av[1];
            As[kq * 4 + 2][m] = av[2]; As[kq * 4 + 3][m] = av[3];
            const int gn = n0 + m;
            f4 bv = {0.f, 0.f, 0.f, 0.f};
            if (gn < N && gk < K) bv = *(const f4*)&B[(long long)gn * ldb + gk];
            Bs[kq * 4 + 0][m] = bv[0]; Bs[kq * 4 + 1][m] = bv[1];
            Bs[kq * 4 + 2][m] = bv[2]; Bs[kq * 4 + 3][m] = bv[3];
        } else if (MODE == MODE_TN) {
            const int k = tid >> 4, q = tid & 15;
            const int gk = k0 + k;
            f4 av = {0.f, 0.f, 0.f, 0.f};
            const int gm = m0 + q * 4;
            if (gk < K && gm < M) av = *(const f4*)&A[(long long)gk * lda + gm];
            *(f4*)&As[k][q * 4] = av;
            f4 bv = {0.f, 0.f, 0.f, 0.f};
            const int gn = n0 + q * 4;
            if (gk < K && gn < N) bv = *(const f4*)&B[(long long)gk * ldb + gn];
            *(f4*)&Bs[k][q * 4] = bv;
        } else { // MODE_CTX
            const int m = tid >> 2, kq = tid & 3;
            const int gk = k0 + kq * 4;
            const int h = gk / 960, j = gk - h * 960;  // float4 never crosses 960-boundary (gk%4==0)
            const int gm = m0 + m;
            f4 av = {0.f, 0.f, 0.f, 0.f};
            if (gm < M) av = *(const f4*)&A[hA * h + (long long)gm * 960 + j];
            As[kq * 4 + 0][m] = av[0]; As[kq * 4 + 1][m] = av[1];
            As[kq * 4 + 2][m] = av[2]; As[kq * 4 + 3][m] = av[3];
            const int gn = n0 + m;
            f4 bv = {0.f, 0.f, 0.f, 0.f};
            if (gn < N) bv = *(const f4*)&B[hB * h + (long long)gn * 960 + j];
            Bs[kq * 4 + 0][m] = bv[0]; Bs[kq * 4 + 1][m] = bv[1];
            Bs[kq * 4 + 2][m] = bv[2]; Bs[kq * 4 + 3][m] = bv[3];
        }
        __syncthreads();
        #pragma unroll
        for (int kk = 0; kk < BK; ++kk) {
            f4 a = *(const f4*)&As[kk][ty * 4];
            f4 b = *(const f4*)&Bs[kk][tx * 4];
            #pragma unroll
            for (int i = 0; i < 4; ++i)
                #pragma unroll
                for (int j2 = 0; j2 < 4; ++j2)
                    acc[i][j2] += a[i] * b[j2];
        }
        __syncthreads();
    }

    #pragma unroll
    for (int i = 0; i < 4; ++i) {
        const int gm = m0 + ty * 4 + i;
        if (gm < M) {
            f4 r = {acc[i][0] * alpha, acc[i][1] * alpha, acc[i][2] * alpha, acc[i][3] * alpha};
            *(f4*)&C[(long long)gm * ldc + n0 + tx * 4] = r;
        }
    }
}

// Partial sums for InstanceNorm stats: part[(z*8+s)*2] = sum, +1 = sumsq
__global__ __launch_bounds__(256)
void stats_part(const float* __restrict__ Sc, float* __restrict__ part, int plane)
{
    const int z = blockIdx.x, s = blockIdx.y;
    const int seg = plane >> 3;
    const float* p = Sc + (long long)z * plane + (long long)s * seg;
    float sum = 0.f, sq = 0.f;
    for (int i = threadIdx.x; i < seg; i += 256) {
        float v = p[i];
        sum += v; sq += v * v;
    }
    #pragma unroll
    for (int o = 32; o > 0; o >>= 1) {
        sum += __shfl_down(sum, o, 64);
        sq  += __shfl_down(sq,  o, 64);
    }
    __shared__ float sh[8];
    const int w = threadIdx.x >> 6;
    if ((threadIdx.x & 63) == 0) { sh[w] = sum; sh[w + 4] = sq; }
    __syncthreads();
    if (threadIdx.x == 0) {
        float S = sh[0] + sh[1] + sh[2] + sh[3];
        float Q = sh[4] + sh[5] + sh[6] + sh[7];
        part[(z * 8 + s) * 2 + 0] = S;
        part[(z * 8 + s) * 2 + 1] = Q;
    }
}

// Row softmax with InstanceNorm scaling. Mean shift cancels in softmax; only
// rs = rsqrt(var+eps) matters (applied pre-softmax). One block per row of 960.
__global__ __launch_bounds__(256)
void softmax_k(float* __restrict__ Sc, const float* __restrict__ part,
               int lg2ch, float pinv)
{
    const int row = blockIdx.x;
    const int z = row >> lg2ch;
    float S = 0.f, Q = 0.f;
    #pragma unroll
    for (int s = 0; s < 8; ++s) {
        S += part[(z * 8 + s) * 2 + 0];
        Q += part[(z * 8 + s) * 2 + 1];
    }
    const float m = S * pinv;
    const float rs = rsqrtf(fmaxf(Q * pinv - m * m, 0.f) + 1e-5f);

    float* p = Sc + (long long)row * 960;
    const int tid = threadIdx.x;
    float loc[4];
    float mx = -1e30f;
    #pragma unroll
    for (int i = 0; i < 4; ++i) {
        const int idx = tid + i * 256;
        const float v = (idx < 960) ? p[idx] * rs : -1e30f;
        loc[i] = v;
        mx = fmaxf(mx, v);
    }
    __shared__ float sh[4];
    #pragma unroll
    for (int o = 32; o > 0; o >>= 1) mx = fmaxf(mx, __shfl_down(mx, o, 64));
    if ((tid & 63) == 0) sh[tid >> 6] = mx;
    __syncthreads();
    mx = fmaxf(fmaxf(sh[0], sh[1]), fmaxf(sh[2], sh[3]));

    float sum = 0.f;
    #pragma unroll
    for (int i = 0; i < 4; ++i) {
        const int idx = tid + i * 256;
        float e = (idx < 960) ? __expf(loc[i] - mx) : 0.f;
        loc[i] = e;
        sum += e;
    }
    __shared__ float sh2[4];
    #pragma unroll
    for (int o = 32; o > 0; o >>= 1) sum += __shfl_down(sum, o, 64);
    if ((tid & 63) == 0) sh2[tid >> 6] = sum;
    __syncthreads();
    sum = sh2[0] + sh2[1] + sh2[2] + sh2[3];
    const float inv = 1.0f / sum;
    #pragma unroll
    for (int i = 0; i < 4; ++i) {
        const int idx = tid + i * 256;
        if (idx < 960) p[idx] = loc[i] * inv;
    }
}

extern "C" void kernel_launch(void* const* d_in, const int* in_sizes, int n_in,
                              void* d_out, int out_size, void* d_ws, size_t ws_size,
                              hipStream_t stream)
{
    // Input order: emb0..emb3, emb_all, Wq0, Wo0, Wq1, Wo1, Wq2, Wo2, Wq3, Wo3, Wk, Wv
    const float* emb[4]  = {(const float*)d_in[0], (const float*)d_in[1],
                            (const float*)d_in[2], (const float*)d_in[3]};
    const float* emb_all = (const float*)d_in[4];
    const float* Wq[4]   = {(const float*)d_in[5], (const float*)d_in[7],
                            (const float*)d_in[9], (const float*)d_in[11]};
    const float* Wo[4]   = {(const float*)d_in[6], (const float*)d_in[8],
                            (const float*)d_in[10], (const float*)d_in[12]};
    const float* Wk = (const float*)d_in[13];
    const float* Wv = (const float*)d_in[14];
    float* out = (float*)d_out;

    // Workspace layout (floats), total ~254 MB
    float* ws   = (float*)d_ws;
    const long long KV_ELE = 4LL * 16 * 196 * 960;    // 12042240, layout [H][B][N][KV]
    float* Kbuf = ws;
    float* Vbuf = Kbuf + KV_ELE;
    float* Qt   = Vbuf + KV_ELE;                      // [B][H][N][ch]  (max ch=512)
    float* Sc   = Qt + 16LL * 4 * 196 * 512;          // [B][H][ch][960] (max ch=512)
    float* Part = Sc + 16LL * 4 * 512 * 960;          // 64*8*2
    float* Ctx  = Part + 2048;                        // [B][196][ch]

    const int  chs[4]  = {64, 128, 256, 512};
    const int  lg2c[4] = {6, 7, 8, 9};
    const long long ooff[4] = {0, 200704, 602112, 1404928};
    const float inv_sqrt_kv = 0.03227486121839514f;   // 1/sqrt(960)

    dim3 blk(256);

    // --- K, V projections: per-head emb_all[3136,960] @ W[h][960,960]^T ---
    {
        dim3 g(3136 / 64, 960 / 64, 4);
        gemm_k<MODE_NT><<<g, blk, 0, stream>>>(
            emb_all, Wk, Kbuf, 3136, 960, 960, 960, 960, 960,
            1, 0LL, 0LL, 1, 921600LL, 0LL, 3136LL * 960, 0LL, 0LL, 1.0f);
        gemm_k<MODE_NT><<<g, blk, 0, stream>>>(
            emb_all, Wv, Vbuf, 3136, 960, 960, 960, 960, 960,
            1, 0LL, 0LL, 1, 921600LL, 0LL, 3136LL * 960, 0LL, 0LL, 1.0f);
    }

    for (int i = 0; i < 4; ++i) {
        const int ch = chs[i];

        // Qt[b,h,n,d] = sum_c emb[b,n,c] * Wq[h,d,c]   (z = b*4+h)
        dim3 gq((196 + 63) / 64, ch / 64, 64);
        gemm_k<MODE_NT><<<gq, blk, 0, stream>>>(
            emb[i], Wq[i], Qt, 196, ch, ch, ch, ch, ch,
            4, 196LL * ch, 0LL, 4, 0LL, (long long)ch * ch,
            196LL * ch, 0LL, 0LL, 1.0f);

        // Sc[z,d,j] = inv_sqrt_kv * sum_n Qt[z,n,d] * K[h,b,n,j]   (z = b*4+h)
        dim3 gs(ch / 64, 960 / 64, 64);
        gemm_k<MODE_TN><<<gs, blk, 0, stream>>>(
            Qt, Kbuf, Sc, ch, 960, 196, ch, 960, 960,
            1, 196LL * ch, 0LL, 4, 196LL * 960, 16LL * 196 * 960,
            (long long)ch * 960, 0LL, 0LL, inv_sqrt_kv);

        // InstanceNorm stats + row softmax (in place on Sc)
        stats_part<<<dim3(64, 8), blk, 0, stream>>>(Sc, Part, ch * 960);
        softmax_k<<<dim3(64 * ch), blk, 0, stream>>>(Sc, Part, lg2c[i], 1.0f / (ch * 960));

        // Ctx[b,n,d] = 1/4 * sum_h sum_j V[h,b,n,j] * Sc[(b*4+h),d,j]   (z = b)
        dim3 gc((196 + 63) / 64, ch / 64, 16);
        gemm_k<MODE_CTX><<<gc, blk, 0, stream>>>(
            Vbuf, Sc, Ctx, 196, ch, 3840, 960, 960, ch,
            1, 196LL * 960, 0LL, 1, 4LL * ch * 960, 0LL,
            196LL * ch, 16LL * 196 * 960, (long long)ch * 960, 0.25f);

        // out[b,n,e] = sum_d Ctx[b,n,d] * Wo[e,d]   (z = b)
        gemm_k<MODE_NT><<<gc, blk, 0, stream>>>(
            Ctx, Wo[i], out + ooff[i], 196, ch, ch, ch, ch, ch,
            1, 196LL * ch, 0LL, 1, 0LL, 0LL,
            196LL * ch, 0LL, 0LL, 1.0f);
    }
}

// Round 2
// 945.782 us; speedup vs baseline: 2.7726x; 2.7726x over previous
//
#include <hip/hip_runtime.h>

typedef _Float16 half_t;
typedef _Float16 h8 __attribute__((ext_vector_type(8)));
typedef _Float16 h4 __attribute__((ext_vector_type(4)));
typedef float f4v __attribute__((ext_vector_type(4)));

__device__ __forceinline__ int div196(int m) { return (m * 21400) >> 22; }  // exact for m<=3135

// ---------------- cast fp32 -> fp16, 15 segments in one launch ----------------
struct CastArgs {
    const float* src[15];
    half_t* dst[15];
    int n[15];
};

__global__ __launch_bounds__(256) void cast_k(CastArgs a)
{
    const int seg = blockIdx.y;
    const int n = a.n[seg];
    const int i8 = (blockIdx.x * 256 + threadIdx.x) * 8;
    if (i8 >= n) return;
    const float* s = a.src[seg] + i8;
    f4v v0 = *(const f4v*)s;
    f4v v1 = *(const f4v*)(s + 4);
    h8 o;
    o[0] = (half_t)v0[0]; o[1] = (half_t)v0[1]; o[2] = (half_t)v0[2]; o[3] = (half_t)v0[3];
    o[4] = (half_t)v1[0]; o[5] = (half_t)v1[1]; o[6] = (half_t)v1[2]; o[7] = (half_t)v1[3];
    *(h8*)(a.dst[seg] + i8) = o;
}

// ---------------- staged tile load with k-limit masking ----------------
template<bool CK>
__device__ __forceinline__ h8 ldtile(const half_t* __restrict__ base, int row, int kb,
                                     int ld, long long hstr, int rowLim, int Klim)
{
    h8 v = {0, 0, 0, 0, 0, 0, 0, 0};
    if (row >= rowLim) return v;
    const half_t* p;
    if (CK) {
        const int hh = kb / 960;
        p = base + (long long)hh * hstr + (long long)row * ld + (kb - hh * 960);
    } else {
        p = base + (long long)row * ld + kb;
    }
    if (kb + 8 <= Klim) return *(const h8*)p;
    #pragma unroll
    for (int e = 0; e < 8; ++e) if (kb + e < Klim) v[e] = p[e];
    return v;
}

// ---------------- MFMA GEMM: C[m,n] = alpha * sum_k A(m,k)*B(n,k) ----------------
// block 64x64 (128 threads, 2 waves, wave tile 64x32), BK=32, mfma_f32_16x16x32_f16.
// OUT: 0 = fp32 normal, 1 = fp16 normal, 2 = fp16 transposed (C[n][m], row-comp optional)
// CK : composite k = (h, j), h = k/960, adds h*hA / h*hB to the address.
template<int OUT, bool CK>
__global__ __launch_bounds__(128)
void gemm_h(const half_t* __restrict__ Ag, const half_t* __restrict__ Bg,
            void* __restrict__ Cg, int Mlim, int Klim, int nKt,
            int lda, int ldb, int ldc,
            int divA, long long sAhi, long long sAlo, long long hA,
            int divB, long long sBhi, long long sBlo, long long hB,
            long long sC, long long tStrB, int tComp, float alpha)
{
    __shared__ __align__(16) half_t SM[64 * 72];      // 9216 B, reused by transpose epilogue
    half_t (*As)[32] = (half_t(*)[32])SM;
    half_t (*Bs)[32] = (half_t(*)[32])(SM + 2048);

    const int z = blockIdx.z;
    const half_t* A = Ag + (long long)(z / divA) * sAhi + (long long)(z % divA) * sAlo;
    const half_t* B = Bg + (long long)(z / divB) * sBhi + (long long)(z % divB) * sBlo;
    const int m0 = blockIdx.x * 64, n0 = blockIdx.y * 64;
    const int tid = threadIdx.x;
    const int lane = tid & 63, w = tid >> 6;
    const int l15 = lane & 15, q = lane >> 4;

    const int r0 = tid >> 2, kg = tid & 3;            // staging coords (2 loads/thread)
    const int r1 = r0 + 32;

    f4v acc[4][2];
    #pragma unroll
    for (int i = 0; i < 4; ++i)
        #pragma unroll
        for (int j = 0; j < 2; ++j) acc[i][j] = (f4v){0.f, 0.f, 0.f, 0.f};

    for (int kt = 0; kt < nKt; ++kt) {
        const int kb = kt * 32 + kg * 8;
        h8 a0 = ldtile<CK>(A, m0 + r0, kb, lda, hA, Mlim, Klim);
        h8 a1 = ldtile<CK>(A, m0 + r1, kb, lda, hA, Mlim, Klim);
        h8 b0 = ldtile<CK>(B, n0 + r0, kb, ldb, hB, 1 << 30, Klim);
        h8 b1 = ldtile<CK>(B, n0 + r1, kb, ldb, hB, 1 << 30, Klim);
        __syncthreads();
        *(h8*)&As[r0][kg * 8] = a0;
        *(h8*)&As[r1][kg * 8] = a1;
        *(h8*)&Bs[r0][kg * 8] = b0;
        *(h8*)&Bs[r1][kg * 8] = b1;
        __syncthreads();
        h8 af[4], bf[2];
        #pragma unroll
        for (int mt = 0; mt < 4; ++mt) af[mt] = *(h8*)&As[mt * 16 + l15][q * 8];
        #pragma unroll
        for (int nt = 0; nt < 2; ++nt) bf[nt] = *(h8*)&Bs[w * 32 + nt * 16 + l15][q * 8];
        #pragma unroll
        for (int mt = 0; mt < 4; ++mt)
            #pragma unroll
            for (int nt = 0; nt < 2; ++nt)
                acc[mt][nt] = __builtin_amdgcn_mfma_f32_16x16x32_f16(af[mt], bf[nt], acc[mt][nt], 0, 0, 0);
    }

    if (OUT == 0) {
        float* Cz = (float*)Cg + (long long)z * sC;
        #pragma unroll
        for (int mt = 0; mt < 4; ++mt)
            #pragma unroll
            for (int r = 0; r < 4; ++r) {
                const int row = m0 + mt * 16 + q * 4 + r;
                if (row < Mlim) {
                    #pragma unroll
                    for (int nt = 0; nt < 2; ++nt) {
                        const int col = n0 + w * 32 + nt * 16 + l15;
                        Cz[(long long)row * ldc + col] = acc[mt][nt][r] * alpha;
                    }
                }
            }
    } else if (OUT == 1) {
        half_t* Cz = (half_t*)Cg + (long long)z * sC;
        #pragma unroll
        for (int mt = 0; mt < 4; ++mt)
            #pragma unroll
            for (int r = 0; r < 4; ++r) {
                const int row = m0 + mt * 16 + q * 4 + r;
                if (row < Mlim) {
                    #pragma unroll
                    for (int nt = 0; nt < 2; ++nt) {
                        const int col = n0 + w * 32 + nt * 16 + l15;
                        Cz[(long long)row * ldc + col] = (half_t)(acc[mt][nt][r] * alpha);
                    }
                }
            }
    } else {
        // transpose epilogue: acc -> LDS Tt[n][m] -> coalesced global C[n][m]
        __syncthreads();
        half_t (*Tt)[72] = (half_t(*)[72])SM;
        #pragma unroll
        for (int mt = 0; mt < 4; ++mt)
            #pragma unroll
            for (int nt = 0; nt < 2; ++nt) {
                h4 pk;
                #pragma unroll
                for (int r = 0; r < 4; ++r) pk[r] = (half_t)(acc[mt][nt][r] * alpha);
                *(h4*)&Tt[w * 32 + nt * 16 + l15][mt * 16 + q * 4] = pk;
            }
        __syncthreads();
        half_t* Cz = (half_t*)Cg + (long long)z * sC;
        const int jl = tid >> 1, mh = (tid & 1) * 32;
        #pragma unroll
        for (int g = 0; g < 4; ++g) {
            const int ml = mh + g * 8;
            const int mg = m0 + ml;
            h8 v = *(h8*)&Tt[jl][ml];
            if (tComp) {
                const int b0 = div196(mg), b1 = div196(mg + 7);
                if (b0 == b1) {
                    half_t* rp = Cz + (long long)b0 * tStrB + (long long)(n0 + jl) * ldc + (mg - 196 * b0);
                    h4 lo = {v[0], v[1], v[2], v[3]};
                    h4 hi = {v[4], v[5], v[6], v[7]};
                    *(h4*)rp = lo;
                    *(h4*)(rp + 4) = hi;
                } else {
                    #pragma unroll
                    for (int e = 0; e < 8; ++e) {
                        const int m = mg + e;
                        const int b = div196(m);
                        Cz[(long long)b * tStrB + (long long)(n0 + jl) * ldc + (m - 196 * b)] = v[e];
                    }
                }
            } else {
                if (mg + 8 <= Mlim) {
                    *(h8*)(Cz + (long long)(n0 + jl) * ldc + mg) = v;
                } else {
                    #pragma unroll
                    for (int e = 0; e < 8; ++e)
                        if (mg + e < Mlim) Cz[(long long)(n0 + jl) * ldc + mg + e] = v[e];
                }
            }
        }
    }
}

// ---------------- InstanceNorm stats: partial sum/sumsq per (z, 1/8 segment) ----------------
__global__ __launch_bounds__(256)
void stats_part(const float* __restrict__ Sc, float* __restrict__ part, int plane)
{
    const int z = blockIdx.x, s = blockIdx.y;
    const int seg4 = plane >> 5;   // (plane/8)/4 float4s
    const f4v* p = (const f4v*)(Sc + (long long)z * plane + (long long)s * (plane >> 3));
    float sum = 0.f, sq = 0.f;
    for (int i = threadIdx.x; i < seg4; i += 256) {
        f4v v = p[i];
        sum += v[0] + v[1] + v[2] + v[3];
        sq  += v[0] * v[0] + v[1] * v[1] + v[2] * v[2] + v[3] * v[3];
    }
    #pragma unroll
    for (int o = 32; o > 0; o >>= 1) {
        sum += __shfl_down(sum, o, 64);
        sq  += __shfl_down(sq,  o, 64);
    }
    __shared__ float sh[8];
    const int wv = threadIdx.x >> 6;
    if ((threadIdx.x & 63) == 0) { sh[wv] = sum; sh[wv + 4] = sq; }
    __syncthreads();
    if (threadIdx.x == 0) {
        part[(z * 8 + s) * 2 + 0] = sh[0] + sh[1] + sh[2] + sh[3];
        part[(z * 8 + s) * 2 + 1] = sh[4] + sh[5] + sh[6] + sh[7];
    }
}

// ---------------- row softmax with IN scaling; writes fp16 probs in-place ----------------
__global__ __launch_bounds__(256)
void softmax_k(float* __restrict__ Sc, const float* __restrict__ part,
               int lg2ch, float pinv)
{
    const long long row = blockIdx.x;
    const int z = (int)(row >> lg2ch);
    float S = 0.f, Q = 0.f;
    #pragma unroll
    for (int s = 0; s < 8; ++s) {
        S += part[(z * 8 + s) * 2 + 0];
        Q += part[(z * 8 + s) * 2 + 1];
    }
    const float m = S * pinv;
    const float rs = rsqrtf(fmaxf(Q * pinv - m * m, 0.f) + 1e-5f);

    float* p = Sc + row * 960;
    half_t* op = (half_t*)Sc + row * 1920;   // in-place fp16 (first half of the fp32 row)
    const int tid = threadIdx.x;
    float loc[4];
    float mx = -1e30f;
    #pragma unroll
    for (int i = 0; i < 4; ++i) {
        const int idx = tid + i * 256;
        const float v = (idx < 960) ? p[idx] * rs : -1e30f;
        loc[i] = v;
        mx = fmaxf(mx, v);
    }
    __shared__ float sh[4];
    #pragma unroll
    for (int o = 32; o > 0; o >>= 1) mx = fmaxf(mx, __shfl_down(mx, o, 64));
    if ((tid & 63) == 0) sh[tid >> 6] = mx;
    __syncthreads();
    mx = fmaxf(fmaxf(sh[0], sh[1]), fmaxf(sh[2], sh[3]));

    float sum = 0.f;
    #pragma unroll
    for (int i = 0; i < 4; ++i) {
        const int idx = tid + i * 256;
        float e = (idx < 960) ? __expf(loc[i] - mx) : 0.f;
        loc[i] = e;
        sum += e;
    }
    __shared__ float sh2[4];
    #pragma unroll
    for (int o = 32; o > 0; o >>= 1) sum += __shfl_down(sum, o, 64);
    if ((tid & 63) == 0) sh2[tid >> 6] = sum;
    __syncthreads();
    sum = sh2[0] + sh2[1] + sh2[2] + sh2[3];
    const float inv = 1.0f / sum;
    #pragma unroll
    for (int i = 0; i < 4; ++i) {
        const int idx = tid + i * 256;
        if (idx < 960) op[idx] = (half_t)(loc[i] * inv);
    }
}

// ---------------- launcher ----------------
extern "C" void kernel_launch(void* const* d_in, const int* in_sizes, int n_in,
                              void* d_out, int out_size, void* d_ws, size_t ws_size,
                              hipStream_t stream)
{
    const float* emb[4]  = {(const float*)d_in[0], (const float*)d_in[1],
                            (const float*)d_in[2], (const float*)d_in[3]};
    const float* emb_all = (const float*)d_in[4];
    const float* Wq[4]   = {(const float*)d_in[5], (const float*)d_in[7],
                            (const float*)d_in[9], (const float*)d_in[11]};
    const float* Wo[4]   = {(const float*)d_in[6], (const float*)d_in[8],
                            (const float*)d_in[10], (const float*)d_in[12]};
    const float* Wk = (const float*)d_in[13];
    const float* Wv = (const float*)d_in[14];
    float* out = (float*)d_out;

    // fp16 workspace layout (half elements)
    half_t* hb = (half_t*)d_ws;
    half_t* EAh = hb;                              // 3010560
    half_t* Eh  = EAh + 3010560;                   // 3010560
    half_t* Wkh = Eh  + 3010560;                   // 3686400
    half_t* Wvh = Wkh + 3686400;                   // 3686400
    half_t* Wqh = Wvh + 3686400;                   // 1392640
    half_t* Woh = Wqh + 1392640;                   // 348160
    half_t* KT  = Woh + 348160;                    // [h][b][960][208] = 12779520
    half_t* Vh  = KT  + 12779520;                  // [h][3136][960]  = 12042240
    half_t* QtT = Vh  + 12042240;                  // [z][ch][208] max = 6815744
    half_t* Ctx = QtT + 6815744;                   // [b][196][ch] max = 1605632
    float*  Scf  = (float*)(Ctx + 1605632);        // [64][ch][960] fp32, doubles as fp16 P
    float*  Part = Scf + 31457280;                 // 1024 floats

    const int  chs[4]   = {64, 128, 256, 512};
    const int  lg2c[4]  = {6, 7, 8, 9};
    const long long offE[4] = {0, 200704, 602112, 1404928};
    const long long offQ[4] = {0, 16384, 81920, 344064};
    const long long offO[4] = {0, 4096, 20480, 86016};
    const long long ooff[4] = {0, 200704, 602112, 1404928};
    const float inv_sqrt_kv = 0.03227486121839514f;

    // ---- casts (one launch, 15 segments) ----
    CastArgs ca;
    ca.src[0] = emb_all; ca.dst[0] = EAh; ca.n[0] = 3010560;
    for (int i = 0; i < 4; ++i) {
        ca.src[1 + i] = emb[i]; ca.dst[1 + i] = Eh + offE[i]; ca.n[1 + i] = (int)(3136LL * chs[i]);
    }
    ca.src[5] = Wk; ca.dst[5] = Wkh; ca.n[5] = 3686400;
    ca.src[6] = Wv; ca.dst[6] = Wvh; ca.n[6] = 3686400;
    for (int i = 0; i < 4; ++i) {
        ca.src[7 + i]  = Wq[i]; ca.dst[7 + i]  = Wqh + offQ[i]; ca.n[7 + i]  = 4 * chs[i] * chs[i];
        ca.src[11 + i] = Wo[i]; ca.dst[11 + i] = Woh + offO[i]; ca.n[11 + i] = chs[i] * chs[i];
    }
    cast_k<<<dim3(1800, 15), 256, 0, stream>>>(ca);

    // ---- K (transposed out) and V (normal out) projections, z = h ----
    {
        dim3 g(49, 15, 4);
        gemm_h<2, false><<<g, 128, 0, stream>>>(
            EAh, Wkh, KT, 3136, 960, 30, 960, 960, 208,
            1, 0, 0, 0, 1, 921600, 0, 0,
            3194880LL, 199680LL, 1, 1.0f);
        gemm_h<1, false><<<g, 128, 0, stream>>>(
            EAh, Wvh, Vh, 3136, 960, 30, 960, 960, 960,
            1, 0, 0, 0, 1, 921600, 0, 0,
            3010560LL, 0, 0, 1.0f);
    }

    for (int i = 0; i < 4; ++i) {
        const int ch = chs[i];
        const long long llch = ch;

        // Q-proj -> QtT[z=4b+h][d][n(208)]  (transposed epilogue, no row-comp)
        gemm_h<2, false><<<dim3(4, ch / 64, 64), 128, 0, stream>>>(
            Eh + offE[i], Wqh + offQ[i], QtT, 196, ch, ch / 32, ch, ch, 208,
            4, 196LL * ch, 0, 0, 4, 0, llch * ch, 0,
            llch * 208, 0, 0, 1.0f);

        // Sc[z][d][960] fp32 = inv_sqrt_kv * QtT[z] x KT[h][b]
        gemm_h<0, false><<<dim3(ch / 64, 15, 64), 128, 0, stream>>>(
            QtT, KT, Scf, ch, 196, 7, 208, 208, 960,
            1, llch * 208, 0, 0, 4, 199680LL, 3194880LL, 0,
            llch * 960, 0, 0, inv_sqrt_kv);

        // stats + softmax (writes fp16 P in-place)
        stats_part<<<dim3(64, 8), 256, 0, stream>>>(Scf, Part, ch * 960);
        softmax_k<<<dim3(64 * ch), 256, 0, stream>>>(Scf, Part, lg2c[i], 1.0f / (ch * 960));

        // ctx[b][n][d] fp16 = 0.25 * sum_{h,j} V[h][b*196+n][j] * P[4b+h][d][j]
        gemm_h<1, true><<<dim3(4, ch / 64, 16), 128, 0, stream>>>(
            Vh, (half_t*)Scf, Ctx, 196, 3840, 120, 960, 1920, ch,
            1, 188160LL, 0, 3010560LL, 1, 4LL * ch * 1920, 0, llch * 1920,
            196LL * ch, 0, 0, 0.25f);

        // out[b][n][e] fp32 = ctx x Wo^T
        gemm_h<0, false><<<dim3(4, ch / 64, 16), 128, 0, stream>>>(
            Ctx, Woh + offO[i], out + ooff[i], 196, ch, ch / 32, ch, ch, ch,
            1, 196LL * ch, 0, 0, 1, 0, 0, 0,
            196LL * ch, 0, 0, 1.0f);
    }
}

// Round 3
// 796.230 us; speedup vs baseline: 3.2934x; 1.1878x over previous
//
#include <hip/hip_runtime.h>

typedef _Float16 half_t;
typedef _Float16 h8 __attribute__((ext_vector_type(8)));
typedef _Float16 h4 __attribute__((ext_vector_type(4)));
typedef float f4v __attribute__((ext_vector_type(4)));

__device__ __forceinline__ int div196(int m) { return (m * 21400) >> 22; }  // exact for m<=3135

// ---------------- cast fp32 -> fp16, 11 segments in one launch ----------------
struct CastArgs {
    const float* src[11];
    half_t* dst[11];
    int n[11];
};

__global__ __launch_bounds__(256) void cast_k(CastArgs a)
{
    const int seg = blockIdx.y;
    const int n = a.n[seg];
    const int i8 = (blockIdx.x * 256 + threadIdx.x) * 8;
    if (i8 >= n) return;
    const float* s = a.src[seg] + i8;
    f4v v0 = *(const f4v*)s;
    f4v v1 = *(const f4v*)(s + 4);
    h8 o;
    o[0] = (half_t)v0[0]; o[1] = (half_t)v0[1]; o[2] = (half_t)v0[2]; o[3] = (half_t)v0[3];
    o[4] = (half_t)v1[0]; o[5] = (half_t)v1[1]; o[6] = (half_t)v1[2]; o[7] = (half_t)v1[3];
    *(h8*)(a.dst[seg] + i8) = o;
}

// ---------------- Wo replication: Wo4[e][r*ch+d] = (half)Wo[e][d], r=0..3 ----------------
struct ReplArgs {
    const float* src[4];
    half_t* dst[4];
    int n[4];
    int lg2[4];
};

__global__ __launch_bounds__(256) void repl_k(ReplArgs a)
{
    const int seg = blockIdx.y;
    const int n = a.n[seg];
    const int i8 = (blockIdx.x * 256 + threadIdx.x) * 8;
    if (i8 >= n) return;
    const int lg = a.lg2[seg], ch = 1 << lg;
    const int e = i8 >> lg, d = i8 & (ch - 1);
    const float* s = a.src[seg] + i8;
    f4v v0 = *(const f4v*)s;
    f4v v1 = *(const f4v*)(s + 4);
    h8 o;
    o[0] = (half_t)v0[0]; o[1] = (half_t)v0[1]; o[2] = (half_t)v0[2]; o[3] = (half_t)v0[3];
    o[4] = (half_t)v1[0]; o[5] = (half_t)v1[1]; o[6] = (half_t)v1[2]; o[7] = (half_t)v1[3];
    half_t* base = a.dst[seg] + ((long long)e << (lg + 2)) + d;
    #pragma unroll
    for (int r = 0; r < 4; ++r) *(h8*)(base + r * ch) = o;
}

// ---------------- staged tile load with k-limit masking ----------------
__device__ __forceinline__ h8 ldtile(const half_t* __restrict__ base, int row, int kb,
                                     int ld, int rowLim, int Klim)
{
    h8 v = {0, 0, 0, 0, 0, 0, 0, 0};
    if (row >= rowLim) return v;
    const half_t* p = base + (long long)row * ld + kb;
    if (kb + 8 <= Klim) return *(const h8*)p;
    #pragma unroll
    for (int e = 0; e < 8; ++e) if (kb + e < Klim) v[e] = p[e];
    return v;
}

// ---------------- MFMA GEMM: C[m,n] = alpha * sum_k A(m,k)*B(n,k) ----------------
// block 64x64 (128 threads, 2 waves, wave tile 64x32), BK=32, mfma_f32_16x16x32_f16.
// OUT: 0 = fp32 normal, 1 = fp16 normal, 2 = fp16 transposed (C[n][m], row-split optional)
// STATS: epilogue block-reduces sum/sumsq of stored values into PartOut (OUT=0 only).
template<int OUT, bool STATS>
__global__ __launch_bounds__(128)
void gemm_h(const half_t* __restrict__ Ag, const half_t* __restrict__ Bg,
            void* __restrict__ Cg, float* __restrict__ PartOut,
            int Mlim, int Klim, int nKt,
            int lda, int ldb, int ldc,
            int divA, long long sAhi, long long sAlo,
            int divB, long long sBhi, long long sBlo,
            int divC, long long sChi, long long sClo,
            long long tStrB, int tComp, float alpha)
{
    __shared__ __align__(16) half_t SM[64 * 72];      // 9216 B, reused by transpose epilogue
    half_t (*As)[32] = (half_t(*)[32])SM;
    half_t (*Bs)[32] = (half_t(*)[32])(SM + 2048);
    __shared__ float red[4];

    const int z = blockIdx.z;
    const half_t* A = Ag + (long long)(z / divA) * sAhi + (long long)(z % divA) * sAlo;
    const half_t* B = Bg + (long long)(z / divB) * sBhi + (long long)(z % divB) * sBlo;
    const int m0 = blockIdx.x * 64, n0 = blockIdx.y * 64;
    const int tid = threadIdx.x;
    const int lane = tid & 63, w = tid >> 6;
    const int l15 = lane & 15, q = lane >> 4;

    const int r0 = tid >> 2, kg = tid & 3;            // staging coords (2 loads/thread)
    const int r1 = r0 + 32;

    f4v acc[4][2];
    #pragma unroll
    for (int i = 0; i < 4; ++i)
        #pragma unroll
        for (int j = 0; j < 2; ++j) acc[i][j] = (f4v){0.f, 0.f, 0.f, 0.f};

    for (int kt = 0; kt < nKt; ++kt) {
        const int kb = kt * 32 + kg * 8;
        h8 a0 = ldtile(A, m0 + r0, kb, lda, Mlim, Klim);
        h8 a1 = ldtile(A, m0 + r1, kb, lda, Mlim, Klim);
        h8 b0 = ldtile(B, n0 + r0, kb, ldb, 1 << 30, Klim);
        h8 b1 = ldtile(B, n0 + r1, kb, ldb, 1 << 30, Klim);
        __syncthreads();
        *(h8*)&As[r0][kg * 8] = a0;
        *(h8*)&As[r1][kg * 8] = a1;
        *(h8*)&Bs[r0][kg * 8] = b0;
        *(h8*)&Bs[r1][kg * 8] = b1;
        __syncthreads();
        h8 af[4], bf[2];
        #pragma unroll
        for (int mt = 0; mt < 4; ++mt) af[mt] = *(h8*)&As[mt * 16 + l15][q * 8];
        #pragma unroll
        for (int nt = 0; nt < 2; ++nt) bf[nt] = *(h8*)&Bs[w * 32 + nt * 16 + l15][q * 8];
        #pragma unroll
        for (int mt = 0; mt < 4; ++mt)
            #pragma unroll
            for (int nt = 0; nt < 2; ++nt)
                acc[mt][nt] = __builtin_amdgcn_mfma_f32_16x16x32_f16(af[mt], bf[nt], acc[mt][nt], 0, 0, 0);
    }

    if (OUT == 0) {
        float* Cz = (float*)Cg + (long long)(z / divC) * sChi + (long long)(z % divC) * sClo;
        #pragma unroll
        for (int mt = 0; mt < 4; ++mt)
            #pragma unroll
            for (int r = 0; r < 4; ++r) {
                const int row = m0 + mt * 16 + q * 4 + r;
                if (row < Mlim) {
                    #pragma unroll
                    for (int nt = 0; nt < 2; ++nt) {
                        const int col = n0 + w * 32 + nt * 16 + l15;
                        Cz[(long long)row * ldc + col] = acc[mt][nt][r] * alpha;
                    }
                }
            }
        if (STATS) {
            float s = 0.f, qq = 0.f;
            #pragma unroll
            for (int mt = 0; mt < 4; ++mt)
                #pragma unroll
                for (int nt = 0; nt < 2; ++nt)
                    #pragma unroll
                    for (int r = 0; r < 4; ++r) {
                        const float v = acc[mt][nt][r] * alpha;
                        s += v; qq += v * v;
                    }
            #pragma unroll
            for (int o = 32; o > 0; o >>= 1) {
                s  += __shfl_down(s,  o, 64);
                qq += __shfl_down(qq, o, 64);
            }
            if (lane == 0) { red[w] = s; red[w + 2] = qq; }
            __syncthreads();
            if (tid == 0) {
                const int pidx = blockIdx.y * gridDim.x + blockIdx.x;
                PartOut[((long long)z * 120 + pidx) * 2 + 0] = red[0] + red[1];
                PartOut[((long long)z * 120 + pidx) * 2 + 1] = red[2] + red[3];
            }
        }
    } else if (OUT == 1) {
        half_t* Cz = (half_t*)Cg + (long long)(z / divC) * sChi + (long long)(z % divC) * sClo;
        #pragma unroll
        for (int mt = 0; mt < 4; ++mt)
            #pragma unroll
            for (int r = 0; r < 4; ++r) {
                const int row = m0 + mt * 16 + q * 4 + r;
                if (row < Mlim) {
                    #pragma unroll
                    for (int nt = 0; nt < 2; ++nt) {
                        const int col = n0 + w * 32 + nt * 16 + l15;
                        Cz[(long long)row * ldc + col] = (half_t)(acc[mt][nt][r] * alpha);
                    }
                }
            }
    } else {
        // transpose epilogue: acc -> LDS Tt[n][m] -> coalesced global C[n][m]
        __syncthreads();
        half_t (*Tt)[72] = (half_t(*)[72])SM;
        #pragma unroll
        for (int mt = 0; mt < 4; ++mt)
            #pragma unroll
            for (int nt = 0; nt < 2; ++nt) {
                h4 pk;
                #pragma unroll
                for (int r = 0; r < 4; ++r) pk[r] = (half_t)(acc[mt][nt][r] * alpha);
                *(h4*)&Tt[w * 32 + nt * 16 + l15][mt * 16 + q * 4] = pk;
            }
        __syncthreads();
        half_t* Cz = (half_t*)Cg + (long long)(z / divC) * sChi + (long long)(z % divC) * sClo;
        const int jl = tid >> 1, mh = (tid & 1) * 32;
        #pragma unroll
        for (int g = 0; g < 4; ++g) {
            const int ml = mh + g * 8;
            const int mg = m0 + ml;
            h8 v = *(h8*)&Tt[jl][ml];
            if (tComp) {
                const int b0 = div196(mg), b1 = div196(mg + 7);
                if (b0 == b1) {
                    half_t* rp = Cz + (long long)b0 * tStrB + (long long)(n0 + jl) * ldc + (mg - 196 * b0);
                    h4 lo = {v[0], v[1], v[2], v[3]};
                    h4 hi = {v[4], v[5], v[6], v[7]};
                    *(h4*)rp = lo;
                    *(h4*)(rp + 4) = hi;
                } else {
                    #pragma unroll
                    for (int e = 0; e < 8; ++e) {
                        const int m = mg + e;
                        const int b = div196(m);
                        Cz[(long long)b * tStrB + (long long)(n0 + jl) * ldc + (m - 196 * b)] = v[e];
                    }
                }
            } else {
                if (mg + 8 <= Mlim) {
                    *(h8*)(Cz + (long long)(n0 + jl) * ldc + mg) = v;
                } else {
                    #pragma unroll
                    for (int e = 0; e < 8; ++e)
                        if (mg + e < Mlim) Cz[(long long)(n0 + jl) * ldc + mg + e] = v[e];
                }
            }
        }
    }
}

// ---------------- row softmax with IN scaling; reads stat partials, fp16 out in-place ----------------
__global__ __launch_bounds__(256)
void softmax_k(float* __restrict__ Sc, const float* __restrict__ part,
               int lg2ch, int nPart, float pinv)
{
    const long long row = blockIdx.x;
    const int z = (int)(row >> lg2ch);
    const int tid = threadIdx.x;

    float S = 0.f, Q = 0.f;
    for (int j = tid; j < nPart; j += 256) {
        S += part[((long long)z * 120 + j) * 2 + 0];
        Q += part[((long long)z * 120 + j) * 2 + 1];
    }
    #pragma unroll
    for (int o = 32; o > 0; o >>= 1) {
        S += __shfl_down(S, o, 64);
        Q += __shfl_down(Q, o, 64);
    }
    __shared__ float shr[8];
    const int wv = tid >> 6;
    if ((tid & 63) == 0) { shr[wv] = S; shr[wv + 4] = Q; }
    __syncthreads();
    __shared__ float s_rs;
    if (tid == 0) {
        const float Ssum = shr[0] + shr[1] + shr[2] + shr[3];
        const float Qsum = shr[4] + shr[5] + shr[6] + shr[7];
        const float m = Ssum * pinv;
        s_rs = rsqrtf(fmaxf(Qsum * pinv - m * m, 0.f) + 1e-5f);
    }
    __syncthreads();
    const float rs = s_rs;

    float* p = Sc + row * 960;
    half_t* op = (half_t*)Sc + row * 1920;   // in-place fp16 (first half of the fp32 row)
    float loc[4];
    float mx = -1e30f;
    #pragma unroll
    for (int i = 0; i < 4; ++i) {
        const int idx = tid + i * 256;
        const float v = (idx < 960) ? p[idx] * rs : -1e30f;
        loc[i] = v;
        mx = fmaxf(mx, v);
    }
    __shared__ float sh[4];
    #pragma unroll
    for (int o = 32; o > 0; o >>= 1) mx = fmaxf(mx, __shfl_down(mx, o, 64));
    if ((tid & 63) == 0) sh[tid >> 6] = mx;
    __syncthreads();
    mx = fmaxf(fmaxf(sh[0], sh[1]), fmaxf(sh[2], sh[3]));

    float sum = 0.f;
    #pragma unroll
    for (int i = 0; i < 4; ++i) {
        const int idx = tid + i * 256;
        float e = (idx < 960) ? __expf(loc[i] - mx) : 0.f;
        loc[i] = e;
        sum += e;
    }
    __shared__ float sh2[4];
    #pragma unroll
    for (int o = 32; o > 0; o >>= 1) sum += __shfl_down(sum, o, 64);
    if ((tid & 63) == 0) sh2[tid >> 6] = sum;
    __syncthreads();
    sum = sh2[0] + sh2[1] + sh2[2] + sh2[3];
    const float inv = 1.0f / sum;
    #pragma unroll
    for (int i = 0; i < 4; ++i) {
        const int idx = tid + i * 256;
        if (idx < 960) op[idx] = (half_t)(loc[i] * inv);
    }
}

// ---------------- launcher ----------------
extern "C" void kernel_launch(void* const* d_in, const int* in_sizes, int n_in,
                              void* d_out, int out_size, void* d_ws, size_t ws_size,
                              hipStream_t stream)
{
    const float* emb[4]  = {(const float*)d_in[0], (const float*)d_in[1],
                            (const float*)d_in[2], (const float*)d_in[3]};
    const float* emb_all = (const float*)d_in[4];
    const float* Wq[4]   = {(const float*)d_in[5], (const float*)d_in[7],
                            (const float*)d_in[9], (const float*)d_in[11]};
    const float* Wo[4]   = {(const float*)d_in[6], (const float*)d_in[8],
                            (const float*)d_in[10], (const float*)d_in[12]};
    const float* Wk = (const float*)d_in[13];
    const float* Wv = (const float*)d_in[14];
    float* out = (float*)d_out;

    // fp16 workspace layout (half elements), ~234 MB total
    half_t* hb = (half_t*)d_ws;
    half_t* EAh = hb;                              // 3010560
    half_t* Eh  = EAh + 3010560;                   // 3010560
    half_t* Wkh = Eh  + 3010560;                   // 3686400
    half_t* Wvh = Wkh + 3686400;                   // 3686400
    half_t* Wqh = Wvh + 3686400;                   // 1392640
    half_t* Wo4 = Wqh + 1392640;                   // 1392640 (Wo rows replicated 4x)
    half_t* KT  = Wo4 + 1392640;                   // [h][b][960][208] = 12779520
    half_t* Vh  = KT  + 12779520;                  // [h][3136][960]  = 12042240
    half_t* QtT = Vh  + 12042240;                  // [z][ch][208] max = 6815744
    half_t* Ctx = QtT + 6815744;                   // [b][196][4*ch] max = 6422528
    float*  Scf  = (float*)(Ctx + 6422528);        // [64][ch][960] fp32, doubles as fp16 P
    float*  Part = Scf + 31457280;                 // 64*120*2 floats

    const int  chs[4]   = {64, 128, 256, 512};
    const int  lg2c[4]  = {6, 7, 8, 9};
    const long long offE[4] = {0, 200704, 602112, 1404928};
    const long long offQ[4] = {0, 16384, 81920, 344064};   // 4*ch*ch prefix (also Wo4)
    const long long ooff[4] = {0, 200704, 602112, 1404928};
    const float inv_sqrt_kv = 0.03227486121839514f;

    // ---- casts (one launch, 11 segments) ----
    CastArgs ca;
    ca.src[0] = emb_all; ca.dst[0] = EAh; ca.n[0] = 3010560;
    for (int i = 0; i < 4; ++i) {
        ca.src[1 + i] = emb[i]; ca.dst[1 + i] = Eh + offE[i]; ca.n[1 + i] = (int)(3136LL * chs[i]);
    }
    ca.src[5] = Wk; ca.dst[5] = Wkh; ca.n[5] = 3686400;
    ca.src[6] = Wv; ca.dst[6] = Wvh; ca.n[6] = 3686400;
    for (int i = 0; i < 4; ++i) {
        ca.src[7 + i] = Wq[i]; ca.dst[7 + i] = Wqh + offQ[i]; ca.n[7 + i] = 4 * chs[i] * chs[i];
    }
    cast_k<<<dim3(1800, 11), 256, 0, stream>>>(ca);

    // ---- Wo -> Wo4 replication (cast + 4x row-tile) ----
    ReplArgs ra;
    for (int i = 0; i < 4; ++i) {
        ra.src[i] = Wo[i]; ra.dst[i] = Wo4 + offQ[i];
        ra.n[i] = chs[i] * chs[i]; ra.lg2[i] = lg2c[i];
    }
    repl_k<<<dim3(128, 4), 256, 0, stream>>>(ra);

    // ---- K (transposed out -> KT[h][b][j][n208]) and V (normal) projections, z = h ----
    {
        dim3 g(49, 15, 4);
        gemm_h<2, false><<<g, 128, 0, stream>>>(
            EAh, Wkh, KT, nullptr, 3136, 960, 30, 960, 960, 208,
            1, 0, 0, 1, 921600, 0, 1, 3194880LL, 0,
            199680LL, 1, 1.0f);
        gemm_h<1, false><<<g, 128, 0, stream>>>(
            EAh, Wvh, Vh, nullptr, 3136, 960, 30, 960, 960, 960,
            1, 0, 0, 1, 921600, 0, 1, 3010560LL, 0,
            0, 0, 1.0f);
    }

    for (int i = 0; i < 4; ++i) {
        const int ch = chs[i];
        const long long llch = ch;

        // Q-proj -> QtT[z=4b+h][d][n208]  (transposed epilogue)
        gemm_h<2, false><<<dim3(4, ch / 64, 64), 128, 0, stream>>>(
            Eh + offE[i], Wqh + offQ[i], QtT, nullptr, 196, ch, ch / 32, ch, ch, 208,
            4, 196LL * ch, 0, 4, 0, llch * ch, 1, llch * 208, 0,
            0, 0, 1.0f);

        // Sc[z][d][960] fp32 = inv_sqrt_kv * QtT[z] x KT[h][b]  (+ fused stat partials)
        gemm_h<0, true><<<dim3(ch / 64, 15, 64), 128, 0, stream>>>(
            QtT, KT, Scf, Part, ch, 196, 7, 208, 208, 960,
            1, llch * 208, 0, 4, 199680LL, 3194880LL, 1, llch * 960, 0,
            0, 0, inv_sqrt_kv);

        // softmax (reads partials, writes fp16 P in-place)
        softmax_k<<<dim3(64 * ch), 256, 0, stream>>>(
            Scf, Part, lg2c[i], 15 * (ch / 64), 1.0f / (ch * 960));

        // per-head ctx: Ctx[b][n][h*ch+d] = 0.25 * sum_j V[h][b*196+n][j] * P[z][d][j],  z=4b+h
        gemm_h<1, false><<<dim3(4, ch / 64, 64), 128, 0, stream>>>(
            Vh, (half_t*)Scf, Ctx, nullptr, 196, 960, 30, 960, 1920, 4 * ch,
            4, 188160LL, 3010560LL, 1, llch * 1920, 0, 4, 784LL * ch, llch,
            0, 0, 0.25f);

        // out[b][n][e] fp32 = Ctx[b] (196 x 4ch) x Wo4 (ch x 4ch)^T   (h-sum in K)
        gemm_h<0, false><<<dim3(4, ch / 64, 16), 128, 0, stream>>>(
            Ctx, Wo4 + offQ[i], out + ooff[i], nullptr, 196, 4 * ch, ch / 8, 4 * ch, 4 * ch, ch,
            1, 784LL * ch, 0, 1, 0, 0, 1, 196LL * ch, 0,
            0, 0, 1.0f);
    }
}

// Round 4
// 648.909 us; speedup vs baseline: 4.0411x; 1.2270x over previous
//
#include <hip/hip_runtime.h>

typedef _Float16 half_t;
typedef _Float16 h8 __attribute__((ext_vector_type(8)));
typedef _Float16 h4 __attribute__((ext_vector_type(4)));
typedef float f4v __attribute__((ext_vector_type(4)));

__device__ __forceinline__ int div196(int m) { return (m * 21400) >> 22; }  // exact for m<=3135

// ---------------- prep: cast fp32->fp16 (mode 0) or cast+replicate-4 (mode 1) ----------------
struct PrepArgs {
    const float* src[15];
    half_t* dst[15];
    int n[15];
    int mode[15];
    int lg2[15];
};

__global__ __launch_bounds__(256) void prep_k(PrepArgs a)
{
    const int seg = blockIdx.y;
    const int i8 = (blockIdx.x * 256 + threadIdx.x) * 8;
    if (i8 >= a.n[seg]) return;
    const float* s = a.src[seg] + i8;
    f4v v0 = *(const f4v*)s;
    f4v v1 = *(const f4v*)(s + 4);
    h8 o;
    o[0] = (half_t)v0[0]; o[1] = (half_t)v0[1]; o[2] = (half_t)v0[2]; o[3] = (half_t)v0[3];
    o[4] = (half_t)v1[0]; o[5] = (half_t)v1[1]; o[6] = (half_t)v1[2]; o[7] = (half_t)v1[3];
    if (a.mode[seg] == 0) {
        *(h8*)(a.dst[seg] + i8) = o;
    } else {
        const int lg = a.lg2[seg], ch = 1 << lg;
        const int e = i8 >> lg, d = i8 & (ch - 1);
        half_t* base = a.dst[seg] + ((long long)e << (lg + 2)) + d;
        #pragma unroll
        for (int r = 0; r < 4; ++r) *(h8*)(base + r * ch) = o;
    }
}

// ---------------- staged tile load with k-limit masking ----------------
__device__ __forceinline__ h8 ldtile(const half_t* __restrict__ base, int row, int kb,
                                     int ld, int rowLim, int Klim)
{
    h8 v = {0, 0, 0, 0, 0, 0, 0, 0};
    if (row >= rowLim) return v;
    const half_t* p = base + (long long)row * ld + kb;
    if (kb + 8 <= Klim) return *(const h8*)p;
    #pragma unroll
    for (int e = 0; e < 8; ++e) if (kb + e < Klim) v[e] = p[e];
    return v;
}

// ---------------- batched MFMA GEMM over up to 4 heterogeneous "scales" ----------------
// block 64x64 (128 threads, 2 waves, wave tile 64x32), BK=32, mfma_f32_16x16x32_f16.
// blockIdx.x -> (scale s, m-tile, n-tile, z) via cumEnd/mT/nT tables.
// OUT: 0 = fp32 normal, 1 = fp16 normal, 2 = fp16 transposed (C[n][m], tComp row-split)
// STATS: epilogue block-reduces sum/sumsq of (acc*alpha) into Part[s] (stride 240/z).
struct BP {
    const half_t* A[4]; const half_t* B[4]; void* C[4]; float* Part[4];
    int Mlim[4], Klim[4], nKt[4], lda[4], ldb[4], ldc[4];
    int divA[4]; long long sAhi[4], sAlo[4];
    int divB[4]; long long sBhi[4], sBlo[4];
    int divC[4]; long long sChi[4], sClo[4];
    long long tStrB[4]; int tComp[4];
    float alpha[4];
    int mT[4], nT[4];
    int cumEnd[3];
};

template<int OUT, bool STATS>
__global__ __launch_bounds__(128)
void gemm_b(BP P)
{
    __shared__ __align__(16) half_t SM[64 * 72];      // 9216 B, reused by transpose epilogue
    half_t (*As)[32] = (half_t(*)[32])SM;
    half_t (*Bs)[32] = (half_t(*)[32])(SM + 2048);
    __shared__ float red[4];

    int b = blockIdx.x;
    int s = 0, basev = 0;
    #pragma unroll
    for (int i = 0; i < 3; ++i) if (b >= P.cumEnd[i]) { s = i + 1; basev = P.cumEnd[i]; }
    b -= basev;
    const int mTl = P.mT[s], nTl = P.nT[s];
    const int mt = b % mTl;
    const int t2 = b / mTl;
    const int nt = t2 % nTl;
    const int z  = t2 / nTl;

    const half_t* A  = P.A[s] + (long long)(z / P.divA[s]) * P.sAhi[s] + (long long)(z % P.divA[s]) * P.sAlo[s];
    const half_t* Bp = P.B[s] + (long long)(z / P.divB[s]) * P.sBhi[s] + (long long)(z % P.divB[s]) * P.sBlo[s];
    const int Mlim = P.Mlim[s], Klim = P.Klim[s], nKt = P.nKt[s];
    const int lda = P.lda[s], ldb = P.ldb[s], ldc = P.ldc[s];
    const float alpha = P.alpha[s];
    const int m0 = mt * 64, n0 = nt * 64;
    const int tid = threadIdx.x;
    const int lane = tid & 63, w = tid >> 6;
    const int l15 = lane & 15, q = lane >> 4;

    const int r0 = tid >> 2, kg = tid & 3;            // staging coords (2 loads/thread/operand)
    const int r1 = r0 + 32;

    f4v acc[4][2];
    #pragma unroll
    for (int i = 0; i < 4; ++i)
        #pragma unroll
        for (int j = 0; j < 2; ++j) acc[i][j] = (f4v){0.f, 0.f, 0.f, 0.f};

    for (int kt = 0; kt < nKt; ++kt) {
        const int kb = kt * 32 + kg * 8;
        h8 a0 = ldtile(A, m0 + r0, kb, lda, Mlim, Klim);
        h8 a1 = ldtile(A, m0 + r1, kb, lda, Mlim, Klim);
        h8 b0 = ldtile(Bp, n0 + r0, kb, ldb, 1 << 30, Klim);
        h8 b1 = ldtile(Bp, n0 + r1, kb, ldb, 1 << 30, Klim);
        __syncthreads();
        *(h8*)&As[r0][kg * 8] = a0;
        *(h8*)&As[r1][kg * 8] = a1;
        *(h8*)&Bs[r0][kg * 8] = b0;
        *(h8*)&Bs[r1][kg * 8] = b1;
        __syncthreads();
        h8 af[4], bf[2];
        #pragma unroll
        for (int mti = 0; mti < 4; ++mti) af[mti] = *(h8*)&As[mti * 16 + l15][q * 8];
        #pragma unroll
        for (int nti = 0; nti < 2; ++nti) bf[nti] = *(h8*)&Bs[w * 32 + nti * 16 + l15][q * 8];
        #pragma unroll
        for (int mti = 0; mti < 4; ++mti)
            #pragma unroll
            for (int nti = 0; nti < 2; ++nti)
                acc[mti][nti] = __builtin_amdgcn_mfma_f32_16x16x32_f16(af[mti], bf[nti], acc[mti][nti], 0, 0, 0);
    }

    if (OUT == 0) {
        float* Cz = (float*)P.C[s] + (long long)(z / P.divC[s]) * P.sChi[s] + (long long)(z % P.divC[s]) * P.sClo[s];
        #pragma unroll
        for (int mti = 0; mti < 4; ++mti)
            #pragma unroll
            for (int r = 0; r < 4; ++r) {
                const int row = m0 + mti * 16 + q * 4 + r;
                if (row < Mlim) {
                    #pragma unroll
                    for (int nti = 0; nti < 2; ++nti) {
                        const int col = n0 + w * 32 + nti * 16 + l15;
                        Cz[(long long)row * ldc + col] = acc[mti][nti][r] * alpha;
                    }
                }
            }
    } else if (OUT == 1) {
        half_t* Cz = (half_t*)P.C[s] + (long long)(z / P.divC[s]) * P.sChi[s] + (long long)(z % P.divC[s]) * P.sClo[s];
        #pragma unroll
        for (int mti = 0; mti < 4; ++mti)
            #pragma unroll
            for (int r = 0; r < 4; ++r) {
                const int row = m0 + mti * 16 + q * 4 + r;
                if (row < Mlim) {
                    #pragma unroll
                    for (int nti = 0; nti < 2; ++nti) {
                        const int col = n0 + w * 32 + nti * 16 + l15;
                        Cz[(long long)row * ldc + col] = (half_t)(acc[mti][nti][r] * alpha);
                    }
                }
            }
    } else {
        // transpose epilogue: acc -> LDS Tt[n][m] -> coalesced global C[n][m]
        __syncthreads();
        half_t (*Tt)[72] = (half_t(*)[72])SM;
        #pragma unroll
        for (int mti = 0; mti < 4; ++mti)
            #pragma unroll
            for (int nti = 0; nti < 2; ++nti) {
                h4 pk;
                #pragma unroll
                for (int r = 0; r < 4; ++r) pk[r] = (half_t)(acc[mti][nti][r] * alpha);
                *(h4*)&Tt[w * 32 + nti * 16 + l15][mti * 16 + q * 4] = pk;
            }
        __syncthreads();
        half_t* Cz = (half_t*)P.C[s] + (long long)(z / P.divC[s]) * P.sChi[s] + (long long)(z % P.divC[s]) * P.sClo[s];
        const long long tStrB = P.tStrB[s];
        const int jl = tid >> 1, mh = (tid & 1) * 32;
        #pragma unroll
        for (int g = 0; g < 4; ++g) {
            const int ml = mh + g * 8;
            const int mg = m0 + ml;
            h8 v = *(h8*)&Tt[jl][ml];
            if (P.tComp[s]) {
                const int b0 = div196(mg), b1 = div196(mg + 7);
                if (b0 == b1) {
                    half_t* rp = Cz + (long long)b0 * tStrB + (long long)(n0 + jl) * ldc + (mg - 196 * b0);
                    h4 lo = {v[0], v[1], v[2], v[3]};
                    h4 hi = {v[4], v[5], v[6], v[7]};
                    *(h4*)rp = lo;
                    *(h4*)(rp + 4) = hi;
                } else {
                    #pragma unroll
                    for (int e = 0; e < 8; ++e) {
                        const int m = mg + e;
                        const int bb = div196(m);
                        Cz[(long long)bb * tStrB + (long long)(n0 + jl) * ldc + (m - 196 * bb)] = v[e];
                    }
                }
            } else {
                if (mg + 8 <= Mlim) {
                    *(h8*)(Cz + (long long)(n0 + jl) * ldc + mg) = v;
                } else {
                    #pragma unroll
                    for (int e = 0; e < 8; ++e)
                        if (mg + e < Mlim) Cz[(long long)(n0 + jl) * ldc + mg + e] = v[e];
                }
            }
        }
    }

    if (STATS) {
        float sv = 0.f, qq = 0.f;
        #pragma unroll
        for (int mti = 0; mti < 4; ++mti)
            #pragma unroll
            for (int nti = 0; nti < 2; ++nti)
                #pragma unroll
                for (int r = 0; r < 4; ++r) {
                    const float v = acc[mti][nti][r] * alpha;
                    sv += v; qq += v * v;
                }
        #pragma unroll
        for (int o = 32; o > 0; o >>= 1) {
            sv += __shfl_down(sv, o, 64);
            qq += __shfl_down(qq, o, 64);
        }
        if (lane == 0) { red[w] = sv; red[w + 2] = qq; }
        __syncthreads();
        if (tid == 0) {
            const int pidx = nt * mTl + mt;
            float* PO = P.Part[s] + (long long)z * 240;
            PO[pidx * 2 + 0] = red[0] + red[1];
            PO[pidx * 2 + 1] = red[2] + red[3];
        }
    }
}

// ---------------- batched row softmax (fp16 in/out, in place), block = 128, 1 row ----------------
struct SMArgs {
    half_t* buf[4];
    const float* part[4];
    int cumRows[3];
    int lg2c[4];
    int nPart[4];
    float pinv[4];
};

__global__ __launch_bounds__(128) void softmax_b(SMArgs a)
{
    int r = blockIdx.x;
    int s = 0, basev = 0;
    #pragma unroll
    for (int i = 0; i < 3; ++i) if (r >= a.cumRows[i]) { s = i + 1; basev = a.cumRows[i]; }
    r -= basev;
    const int z = r >> a.lg2c[s];
    const int tid = threadIdx.x;

    // plane stats from GEMM partials (<=120 entries, one per thread)
    const float* part = a.part[s] + (long long)z * 240;
    float S = 0.f, Q = 0.f;
    if (tid < a.nPart[s]) { S = part[tid * 2]; Q = part[tid * 2 + 1]; }
    #pragma unroll
    for (int o = 32; o > 0; o >>= 1) {
        S += __shfl_down(S, o, 64);
        Q += __shfl_down(Q, o, 64);
    }
    __shared__ float sred[4];
    if ((tid & 63) == 0) { sred[tid >> 6] = S; sred[2 + (tid >> 6)] = Q; }
    __syncthreads();
    __shared__ float s_rs;
    if (tid == 0) {
        const float Ss = sred[0] + sred[1], Qs = sred[2] + sred[3];
        const float m = Ss * a.pinv[s];
        s_rs = rsqrtf(fmaxf(Qs * a.pinv[s] - m * m, 0.f) + 1e-5f);
    }
    __syncthreads();
    const float rs = s_rs;

    half_t* p = a.buf[s] + (long long)r * 960;
    const bool act = tid < 120;
    float loc[8];
    float mx = -1e30f;
    if (act) {
        h8 v = *(h8*)(p + tid * 8);
        #pragma unroll
        for (int e = 0; e < 8; ++e) { loc[e] = (float)v[e] * rs; mx = fmaxf(mx, loc[e]); }
    }
    #pragma unroll
    for (int o = 32; o > 0; o >>= 1) mx = fmaxf(mx, __shfl_down(mx, o, 64));
    __shared__ float sm2[2];
    if ((tid & 63) == 0) sm2[tid >> 6] = mx;
    __syncthreads();
    mx = fmaxf(sm2[0], sm2[1]);

    float sum = 0.f;
    if (act) {
        #pragma unroll
        for (int e = 0; e < 8; ++e) { loc[e] = __expf(loc[e] - mx); sum += loc[e]; }
    }
    #pragma unroll
    for (int o = 32; o > 0; o >>= 1) sum += __shfl_down(sum, o, 64);
    __shared__ float ss2[2];
    if ((tid & 63) == 0) ss2[tid >> 6] = sum;
    __syncthreads();
    const float inv = 1.0f / (ss2[0] + ss2[1]);
    if (act) {
        h8 o8;
        #pragma unroll
        for (int e = 0; e < 8; ++e) o8[e] = (half_t)(loc[e] * inv);
        *(h8*)(p + tid * 8) = o8;
    }
}

// ---------------- launcher ----------------
extern "C" void kernel_launch(void* const* d_in, const int* in_sizes, int n_in,
                              void* d_out, int out_size, void* d_ws, size_t ws_size,
                              hipStream_t stream)
{
    const float* emb[4]  = {(const float*)d_in[0], (const float*)d_in[1],
                            (const float*)d_in[2], (const float*)d_in[3]};
    const float* emb_all = (const float*)d_in[4];
    const float* Wq[4]   = {(const float*)d_in[5], (const float*)d_in[7],
                            (const float*)d_in[9], (const float*)d_in[11]};
    const float* Wo[4]   = {(const float*)d_in[6], (const float*)d_in[8],
                            (const float*)d_in[10], (const float*)d_in[12]};
    const float* Wk = (const float*)d_in[13];
    const float* Wv = (const float*)d_in[14];
    float* out = (float*)d_out;

    // workspace (half elements), ~250 MB
    half_t* hb = (half_t*)d_ws;
    half_t* EAh = hb;                              // 3010560
    half_t* Eh  = EAh + 3010560;                   // 3010560
    half_t* Wkh = Eh  + 3010560;                   // 3686400
    half_t* Wvh = Wkh + 3686400;                   // 3686400
    half_t* Wqh = Wvh + 3686400;                   // 1392640
    half_t* Wo4 = Wqh + 1392640;                   // 1392640
    half_t* KT  = Wo4 + 1392640;                   // [h][b][960][208]      = 12779520
    half_t* Vh  = KT  + 12779520;                  // [h][3136][960]        = 12042240
    half_t* QtT = Vh  + 12042240;                  // per-scale [64][ch][208] = 12779520
    half_t* Ctx = QtT + 12779520;                  // per-scale [16][196][4ch] = 12042240
    half_t* Sch = Ctx + 12042240;                  // per-scale [64][ch][960]  = 58982400
    float*  Part = (float*)(Sch + 58982400);       // 4 * 64 * 240 floats

    const int  chs[4]   = {64, 128, 256, 512};
    const int  lg2c[4]  = {6, 7, 8, 9};
    const long long offE[4]   = {0, 200704, 602112, 1404928};      // 3136*ch prefix
    const long long offQ[4]   = {0, 16384, 81920, 344064};         // 4*ch*ch prefix
    const long long offQt[4]  = {0, 851968, 2555904, 5963776};     // 64*208*ch prefix
    const long long offSc[4]  = {0, 3932160, 11796480, 27525120};  // 64*960*ch prefix
    const long long offCtx[4] = {0, 802816, 2408448, 5619712};     // 16*196*4ch prefix
    const long long ooff[4]   = {0, 200704, 602112, 1404928};
    const float inv_sqrt_kv = 0.03227486121839514f;

    // ---- prep: 15 segments (11 casts + 4 Wo replications) ----
    PrepArgs pa;
    pa.src[0] = emb_all; pa.dst[0] = EAh; pa.n[0] = 3010560; pa.mode[0] = 0; pa.lg2[0] = 0;
    for (int i = 0; i < 4; ++i) {
        pa.src[1 + i] = emb[i]; pa.dst[1 + i] = Eh + offE[i];
        pa.n[1 + i] = (int)(3136LL * chs[i]); pa.mode[1 + i] = 0; pa.lg2[1 + i] = 0;
    }
    pa.src[5] = Wk; pa.dst[5] = Wkh; pa.n[5] = 3686400; pa.mode[5] = 0; pa.lg2[5] = 0;
    pa.src[6] = Wv; pa.dst[6] = Wvh; pa.n[6] = 3686400; pa.mode[6] = 0; pa.lg2[6] = 0;
    for (int i = 0; i < 4; ++i) {
        pa.src[7 + i] = Wq[i]; pa.dst[7 + i] = Wqh + offQ[i];
        pa.n[7 + i] = 4 * chs[i] * chs[i]; pa.mode[7 + i] = 0; pa.lg2[7 + i] = 0;
        pa.src[11 + i] = Wo[i]; pa.dst[11 + i] = Wo4 + offQ[i];
        pa.n[11 + i] = chs[i] * chs[i]; pa.mode[11 + i] = 1; pa.lg2[11 + i] = lg2c[i];
    }
    prep_k<<<dim3(1800, 15), 256, 0, stream>>>(pa);

    // ---- K projection (transposed -> KT[h][b][j][n208]), z = h ----
    {
        BP p{};
        p.A[0] = EAh; p.B[0] = Wkh; p.C[0] = KT; p.Part[0] = nullptr;
        p.Mlim[0] = 3136; p.Klim[0] = 960; p.nKt[0] = 30;
        p.lda[0] = 960; p.ldb[0] = 960; p.ldc[0] = 208;
        p.divA[0] = 1; p.sAhi[0] = 0; p.sAlo[0] = 0;
        p.divB[0] = 1; p.sBhi[0] = 921600; p.sBlo[0] = 0;
        p.divC[0] = 1; p.sChi[0] = 3194880; p.sClo[0] = 0;
        p.tStrB[0] = 199680; p.tComp[0] = 1; p.alpha[0] = 1.0f;
        p.mT[0] = 49; p.nT[0] = 15;
        p.cumEnd[0] = p.cumEnd[1] = p.cumEnd[2] = 2940;
        gemm_b<2, false><<<2940, 128, 0, stream>>>(p);
    }
    // ---- V projection (normal -> Vh[h][3136][960]), z = h ----
    {
        BP p{};
        p.A[0] = EAh; p.B[0] = Wvh; p.C[0] = Vh; p.Part[0] = nullptr;
        p.Mlim[0] = 3136; p.Klim[0] = 960; p.nKt[0] = 30;
        p.lda[0] = 960; p.ldb[0] = 960; p.ldc[0] = 960;
        p.divA[0] = 1; p.sAhi[0] = 0; p.sAlo[0] = 0;
        p.divB[0] = 1; p.sBhi[0] = 921600; p.sBlo[0] = 0;
        p.divC[0] = 1; p.sChi[0] = 3010560; p.sClo[0] = 0;
        p.tStrB[0] = 0; p.tComp[0] = 0; p.alpha[0] = 1.0f;
        p.mT[0] = 49; p.nT[0] = 15;
        p.cumEnd[0] = p.cumEnd[1] = p.cumEnd[2] = 2940;
        gemm_b<1, false><<<2940, 128, 0, stream>>>(p);
    }

    // ---- Q-proj, all scales: QtT[z=4b+h][d][n208] (transposed epilogue) ----
    {
        BP p{};
        int cum = 0;
        for (int s = 0; s < 4; ++s) {
            const int ch = chs[s];
            p.A[s] = Eh + offE[s]; p.B[s] = Wqh + offQ[s]; p.C[s] = QtT + offQt[s]; p.Part[s] = nullptr;
            p.Mlim[s] = 196; p.Klim[s] = ch; p.nKt[s] = ch / 32;
            p.lda[s] = ch; p.ldb[s] = ch; p.ldc[s] = 208;
            p.divA[s] = 4; p.sAhi[s] = 196LL * ch; p.sAlo[s] = 0;
            p.divB[s] = 4; p.sBhi[s] = 0; p.sBlo[s] = (long long)ch * ch;
            p.divC[s] = 1; p.sChi[s] = 208LL * ch; p.sClo[s] = 0;
            p.tStrB[s] = 0; p.tComp[s] = 0; p.alpha[s] = 1.0f;
            p.mT[s] = 4; p.nT[s] = ch / 64;
            cum += 4 * (ch / 64) * 64;
            if (s < 3) p.cumEnd[s] = cum;
        }
        gemm_b<2, false><<<3840, 128, 0, stream>>>(p);
    }

    // ---- Scores, all scales: Sch[z][d][960] fp16 + fused stat partials ----
    {
        BP p{};
        int cum = 0;
        for (int s = 0; s < 4; ++s) {
            const int ch = chs[s];
            p.A[s] = QtT + offQt[s]; p.B[s] = KT; p.C[s] = Sch + offSc[s];
            p.Part[s] = Part + (long long)s * 64 * 240;
            p.Mlim[s] = ch; p.Klim[s] = 196; p.nKt[s] = 7;
            p.lda[s] = 208; p.ldb[s] = 208; p.ldc[s] = 960;
            p.divA[s] = 1; p.sAhi[s] = 208LL * ch; p.sAlo[s] = 0;
            p.divB[s] = 4; p.sBhi[s] = 199680; p.sBlo[s] = 3194880;
            p.divC[s] = 1; p.sChi[s] = 960LL * ch; p.sClo[s] = 0;
            p.tStrB[s] = 0; p.tComp[s] = 0; p.alpha[s] = inv_sqrt_kv;
            p.mT[s] = ch / 64; p.nT[s] = 15;
            cum += (ch / 64) * 15 * 64;
            if (s < 3) p.cumEnd[s] = cum;
        }
        gemm_b<1, true><<<14400, 128, 0, stream>>>(p);
    }

    // ---- softmax, all scales (in place fp16) ----
    {
        SMArgs sa;
        int cum = 0;
        for (int s = 0; s < 4; ++s) {
            const int ch = chs[s];
            sa.buf[s] = Sch + offSc[s];
            sa.part[s] = Part + (long long)s * 64 * 240;
            sa.lg2c[s] = lg2c[s];
            sa.nPart[s] = 15 * (ch / 64);
            sa.pinv[s] = 1.0f / (ch * 960);
            cum += 64 * ch;
            if (s < 3) sa.cumRows[s] = cum;
        }
        softmax_b<<<61440, 128, 0, stream>>>(sa);
    }

    // ---- per-head ctx, all scales: Ctx[b][n][h*ch+d] = 0.25 * sum_j V * P ----
    {
        BP p{};
        int cum = 0;
        for (int s = 0; s < 4; ++s) {
            const int ch = chs[s];
            p.A[s] = Vh; p.B[s] = Sch + offSc[s]; p.C[s] = Ctx + offCtx[s]; p.Part[s] = nullptr;
            p.Mlim[s] = 196; p.Klim[s] = 960; p.nKt[s] = 30;
            p.lda[s] = 960; p.ldb[s] = 960; p.ldc[s] = 4 * ch;
            p.divA[s] = 4; p.sAhi[s] = 188160; p.sAlo[s] = 3010560;
            p.divB[s] = 1; p.sBhi[s] = 960LL * ch; p.sBlo[s] = 0;
            p.divC[s] = 4; p.sChi[s] = 784LL * ch; p.sClo[s] = ch;
            p.tStrB[s] = 0; p.tComp[s] = 0; p.alpha[s] = 0.25f;
            p.mT[s] = 4; p.nT[s] = ch / 64;
            cum += 4 * (ch / 64) * 64;
            if (s < 3) p.cumEnd[s] = cum;
        }
        gemm_b<1, false><<<3840, 128, 0, stream>>>(p);
    }

    // ---- out-proj, all scales: out[b][n][e] fp32 = Ctx (196 x 4ch) x Wo4^T ----
    {
        BP p{};
        int cum = 0;
        for (int s = 0; s < 4; ++s) {
            const int ch = chs[s];
            p.A[s] = Ctx + offCtx[s]; p.B[s] = Wo4 + offQ[s]; p.C[s] = out + ooff[s]; p.Part[s] = nullptr;
            p.Mlim[s] = 196; p.Klim[s] = 4 * ch; p.nKt[s] = ch / 8;
            p.lda[s] = 4 * ch; p.ldb[s] = 4 * ch; p.ldc[s] = ch;
            p.divA[s] = 1; p.sAhi[s] = 784LL * ch; p.sAlo[s] = 0;
            p.divB[s] = 1; p.sBhi[s] = 0; p.sBlo[s] = 0;
            p.divC[s] = 1; p.sChi[s] = 196LL * ch; p.sClo[s] = 0;
            p.tStrB[s] = 0; p.tComp[s] = 0; p.alpha[s] = 1.0f;
            p.mT[s] = 4; p.nT[s] = ch / 64;
            cum += 4 * (ch / 64) * 16;
            if (s < 3) p.cumEnd[s] = cum;
        }
        gemm_b<0, false><<<960, 128, 0, stream>>>(p);
    }
}

// Round 5
// 535.040 us; speedup vs baseline: 4.9011x; 1.2128x over previous
//
#include <hip/hip_runtime.h>

typedef _Float16 half_t;
typedef _Float16 h8 __attribute__((ext_vector_type(8)));
typedef _Float16 h4 __attribute__((ext_vector_type(4)));
typedef float f4v __attribute__((ext_vector_type(4)));

__device__ __forceinline__ int div196(int m) { return (m * 21400) >> 22; }  // exact for m<=3135

// ---------------- prep: cast fp32->fp16 (mode 0) or cast+replicate-4 (mode 1) ----------------
struct PrepArgs {
    const float* src[15];
    half_t* dst[15];
    int n[15];
    int mode[15];
    int lg2[15];
};

__global__ __launch_bounds__(256) void prep_k(PrepArgs a)
{
    const int seg = blockIdx.y;
    const int i8 = (blockIdx.x * 256 + threadIdx.x) * 8;
    if (i8 >= a.n[seg]) return;
    const float* s = a.src[seg] + i8;
    f4v v0 = *(const f4v*)s;
    f4v v1 = *(const f4v*)(s + 4);
    h8 o;
    o[0] = (half_t)v0[0]; o[1] = (half_t)v0[1]; o[2] = (half_t)v0[2]; o[3] = (half_t)v0[3];
    o[4] = (half_t)v1[0]; o[5] = (half_t)v1[1]; o[6] = (half_t)v1[2]; o[7] = (half_t)v1[3];
    if (a.mode[seg] == 0) {
        *(h8*)(a.dst[seg] + i8) = o;
    } else {
        const int lg = a.lg2[seg], ch = 1 << lg;
        const int e = i8 >> lg, d = i8 & (ch - 1);
        half_t* base = a.dst[seg] + ((long long)e << (lg + 2)) + d;
        #pragma unroll
        for (int r = 0; r < 4; ++r) *(h8*)(base + r * ch) = o;
    }
}

// ---------------- staged tile load with k-limit masking ----------------
__device__ __forceinline__ h8 ldtile(const half_t* __restrict__ base, int row, int kb,
                                     int ld, int rowLim, int Klim)
{
    h8 v = {0, 0, 0, 0, 0, 0, 0, 0};
    if (row >= rowLim) return v;
    const half_t* p = base + (long long)row * ld + kb;
    if (kb + 8 <= Klim) return *(const h8*)p;
    #pragma unroll
    for (int e = 0; e < 8; ++e) if (kb + e < Klim) v[e] = p[e];
    return v;
}

// ---------------- batch descriptor for up to 4 heterogeneous "scales" ----------------
struct BP {
    const half_t* A[4]; const half_t* B[4]; void* C[4]; float* Part[4];
    int Mlim[4], Nlim[4], Klim[4], nKt[4], lda[4], ldb[4], ldc[4];
    int divA[4]; long long sAhi[4], sAlo[4];
    int divB[4]; long long sBhi[4], sBlo[4];
    int divC[4]; long long sChi[4], sClo[4];
    long long tStrB[4]; int tComp[4];
    float alpha[4];
    int mT[4], nT[4];
    int cumEnd[3];
    int totW;
};

// ---------------- 64x64 MFMA GEMM (2 waves) — used for transpose epilogues & out-proj ----------------
// OUT: 0 = fp32 normal, 1 = fp16 normal, 2 = fp16 transposed (C[n][m], tComp row-split)
template<int OUT, bool STATS>
__global__ __launch_bounds__(128)
void gemm_b(BP P)
{
    __shared__ __align__(16) half_t SM[64 * 72];
    half_t (*As)[32] = (half_t(*)[32])SM;
    half_t (*Bs)[32] = (half_t(*)[32])(SM + 2048);
    __shared__ float red[4];

    int b = blockIdx.x;
    int s = 0, basev = 0;
    #pragma unroll
    for (int i = 0; i < 3; ++i) if (b >= P.cumEnd[i]) { s = i + 1; basev = P.cumEnd[i]; }
    b -= basev;
    const int mTl = P.mT[s], nTl = P.nT[s];
    const int mt = b % mTl;
    const int t2 = b / mTl;
    const int nt = t2 % nTl;
    const int z  = t2 / nTl;

    const half_t* A  = P.A[s] + (long long)(z / P.divA[s]) * P.sAhi[s] + (long long)(z % P.divA[s]) * P.sAlo[s];
    const half_t* Bp = P.B[s] + (long long)(z / P.divB[s]) * P.sBhi[s] + (long long)(z % P.divB[s]) * P.sBlo[s];
    const int Mlim = P.Mlim[s], Klim = P.Klim[s], nKt = P.nKt[s];
    const int lda = P.lda[s], ldb = P.ldb[s], ldc = P.ldc[s];
    const float alpha = P.alpha[s];
    const int m0 = mt * 64, n0 = nt * 64;
    const int tid = threadIdx.x;
    const int lane = tid & 63, w = tid >> 6;
    const int l15 = lane & 15, q = lane >> 4;

    const int r0 = tid >> 2, kg = tid & 3;
    const int r1 = r0 + 32;

    f4v acc[4][2];
    #pragma unroll
    for (int i = 0; i < 4; ++i)
        #pragma unroll
        for (int j = 0; j < 2; ++j) acc[i][j] = (f4v){0.f, 0.f, 0.f, 0.f};

    for (int kt = 0; kt < nKt; ++kt) {
        const int kb = kt * 32 + kg * 8;
        h8 a0 = ldtile(A, m0 + r0, kb, lda, Mlim, Klim);
        h8 a1 = ldtile(A, m0 + r1, kb, lda, Mlim, Klim);
        h8 b0 = ldtile(Bp, n0 + r0, kb, ldb, 1 << 30, Klim);
        h8 b1 = ldtile(Bp, n0 + r1, kb, ldb, 1 << 30, Klim);
        __syncthreads();
        *(h8*)&As[r0][kg * 8] = a0;
        *(h8*)&As[r1][kg * 8] = a1;
        *(h8*)&Bs[r0][kg * 8] = b0;
        *(h8*)&Bs[r1][kg * 8] = b1;
        __syncthreads();
        h8 af[4], bf[2];
        #pragma unroll
        for (int mti = 0; mti < 4; ++mti) af[mti] = *(h8*)&As[mti * 16 + l15][q * 8];
        #pragma unroll
        for (int nti = 0; nti < 2; ++nti) bf[nti] = *(h8*)&Bs[w * 32 + nti * 16 + l15][q * 8];
        #pragma unroll
        for (int mti = 0; mti < 4; ++mti)
            #pragma unroll
            for (int nti = 0; nti < 2; ++nti)
                acc[mti][nti] = __builtin_amdgcn_mfma_f32_16x16x32_f16(af[mti], bf[nti], acc[mti][nti], 0, 0, 0);
    }

    if (OUT == 0) {
        float* Cz = (float*)P.C[s] + (long long)(z / P.divC[s]) * P.sChi[s] + (long long)(z % P.divC[s]) * P.sClo[s];
        #pragma unroll
        for (int mti = 0; mti < 4; ++mti)
            #pragma unroll
            for (int r = 0; r < 4; ++r) {
                const int row = m0 + mti * 16 + q * 4 + r;
                if (row < Mlim) {
                    #pragma unroll
                    for (int nti = 0; nti < 2; ++nti) {
                        const int col = n0 + w * 32 + nti * 16 + l15;
                        Cz[(long long)row * ldc + col] = acc[mti][nti][r] * alpha;
                    }
                }
            }
    } else if (OUT == 1) {
        half_t* Cz = (half_t*)P.C[s] + (long long)(z / P.divC[s]) * P.sChi[s] + (long long)(z % P.divC[s]) * P.sClo[s];
        #pragma unroll
        for (int mti = 0; mti < 4; ++mti)
            #pragma unroll
            for (int r = 0; r < 4; ++r) {
                const int row = m0 + mti * 16 + q * 4 + r;
                if (row < Mlim) {
                    #pragma unroll
                    for (int nti = 0; nti < 2; ++nti) {
                        const int col = n0 + w * 32 + nti * 16 + l15;
                        Cz[(long long)row * ldc + col] = (half_t)(acc[mti][nti][r] * alpha);
                    }
                }
            }
    } else {
        __syncthreads();
        half_t (*Tt)[72] = (half_t(*)[72])SM;
        #pragma unroll
        for (int mti = 0; mti < 4; ++mti)
            #pragma unroll
            for (int nti = 0; nti < 2; ++nti) {
                h4 pk;
                #pragma unroll
                for (int r = 0; r < 4; ++r) pk[r] = (half_t)(acc[mti][nti][r] * alpha);
                *(h4*)&Tt[w * 32 + nti * 16 + l15][mti * 16 + q * 4] = pk;
            }
        __syncthreads();
        half_t* Cz = (half_t*)P.C[s] + (long long)(z / P.divC[s]) * P.sChi[s] + (long long)(z % P.divC[s]) * P.sClo[s];
        const long long tStrB = P.tStrB[s];
        const int jl = tid >> 1, mh = (tid & 1) * 32;
        #pragma unroll
        for (int g = 0; g < 4; ++g) {
            const int ml = mh + g * 8;
            const int mg = m0 + ml;
            h8 v = *(h8*)&Tt[jl][ml];
            if (P.tComp[s]) {
                const int b0 = div196(mg), b1 = div196(mg + 7);
                if (b0 == b1) {
                    half_t* rp = Cz + (long long)b0 * tStrB + (long long)(n0 + jl) * ldc + (mg - 196 * b0);
                    h4 lo = {v[0], v[1], v[2], v[3]};
                    h4 hi = {v[4], v[5], v[6], v[7]};
                    *(h4*)rp = lo;
                    *(h4*)(rp + 4) = hi;
                } else {
                    #pragma unroll
                    for (int e = 0; e < 8; ++e) {
                        const int m = mg + e;
                        const int bb = div196(m);
                        Cz[(long long)bb * tStrB + (long long)(n0 + jl) * ldc + (m - 196 * bb)] = v[e];
                    }
                }
            } else {
                if (mg + 8 <= Mlim) {
                    *(h8*)(Cz + (long long)(n0 + jl) * ldc + mg) = v;
                } else {
                    #pragma unroll
                    for (int e = 0; e < 8; ++e)
                        if (mg + e < Mlim) Cz[(long long)(n0 + jl) * ldc + mg + e] = v[e];
                }
            }
        }
    }

    if (STATS) {
        float sv = 0.f, qq = 0.f;
        #pragma unroll
        for (int mti = 0; mti < 4; ++mti)
            #pragma unroll
            for (int nti = 0; nti < 2; ++nti)
                #pragma unroll
                for (int r = 0; r < 4; ++r) {
                    const float v = acc[mti][nti][r] * alpha;
                    sv += v; qq += v * v;
                }
        #pragma unroll
        for (int o = 32; o > 0; o >>= 1) {
            sv += __shfl_down(sv, o, 64);
            qq += __shfl_down(qq, o, 64);
        }
        if (lane == 0) { red[w] = sv; red[w + 2] = qq; }
        __syncthreads();
        if (tid == 0) {
            const int pidx = nt * mTl + mt;
            float* PO = P.Part[s] + (long long)z * 240;
            PO[pidx * 2 + 0] = red[0] + red[1];
            PO[pidx * 2 + 1] = red[2] + red[3];
        }
    }
}

// ---------------- 128x128 MFMA GEMM (256 threads, 4 waves of 64x64) ----------------
// XCD-contiguous work partition: work = (blockIdx%8)*per + blockIdx/8.
// Full M/N masking (zero-filled), so STATS sums stay exact.
template<int OUT, bool STATS>
__global__ __launch_bounds__(256)
void gemm_w(BP P)
{
    __shared__ __align__(16) half_t As[128][40];   // +8 halves pad: bank spread for b128 reads
    __shared__ __align__(16) half_t Bs[128][40];
    __shared__ float red[8];

    const int per = gridDim.x >> 3;
    int wk = (blockIdx.x & 7) * per + (blockIdx.x >> 3);
    if (wk >= P.totW) return;
    int s = 0, basev = 0;
    #pragma unroll
    for (int i = 0; i < 3; ++i) if (wk >= P.cumEnd[i]) { s = i + 1; basev = P.cumEnd[i]; }
    wk -= basev;
    const int mTl = P.mT[s], nTl = P.nT[s];
    const int mt = wk % mTl;
    const int t2 = wk / mTl;
    const int nt = t2 % nTl;
    const int z  = t2 / nTl;

    const half_t* A  = P.A[s] + (long long)(z / P.divA[s]) * P.sAhi[s] + (long long)(z % P.divA[s]) * P.sAlo[s];
    const half_t* Bp = P.B[s] + (long long)(z / P.divB[s]) * P.sBhi[s] + (long long)(z % P.divB[s]) * P.sBlo[s];
    const int Mlim = P.Mlim[s], Nlim = P.Nlim[s], Klim = P.Klim[s], nKt = P.nKt[s];
    const int lda = P.lda[s], ldb = P.ldb[s], ldc = P.ldc[s];
    const float alpha = P.alpha[s];
    const int m0 = mt * 128, n0 = nt * 128;
    const int tid = threadIdx.x;
    const int lane = tid & 63, wv = tid >> 6;
    const int wm = wv & 1, wn = wv >> 1;
    const int l15 = lane & 15, q = lane >> 4;

    const int r0 = tid >> 2, kg = tid & 3;         // staging: rows r0 and r0+64, chunk kg

    f4v acc[4][4];
    #pragma unroll
    for (int i = 0; i < 4; ++i)
        #pragma unroll
        for (int j = 0; j < 4; ++j) acc[i][j] = (f4v){0.f, 0.f, 0.f, 0.f};

    for (int kt = 0; kt < nKt; ++kt) {
        const int kb = kt * 32 + kg * 8;
        h8 a0 = ldtile(A, m0 + r0, kb, lda, Mlim, Klim);
        h8 a1 = ldtile(A, m0 + r0 + 64, kb, lda, Mlim, Klim);
        h8 b0 = ldtile(Bp, n0 + r0, kb, ldb, Nlim, Klim);
        h8 b1 = ldtile(Bp, n0 + r0 + 64, kb, ldb, Nlim, Klim);
        __syncthreads();
        *(h8*)&As[r0][kg * 8] = a0;
        *(h8*)&As[r0 + 64][kg * 8] = a1;
        *(h8*)&Bs[r0][kg * 8] = b0;
        *(h8*)&Bs[r0 + 64][kg * 8] = b1;
        __syncthreads();
        h8 af[4], bf[4];
        #pragma unroll
        for (int mi = 0; mi < 4; ++mi) af[mi] = *(h8*)&As[wm * 64 + mi * 16 + l15][q * 8];
        #pragma unroll
        for (int ni = 0; ni < 4; ++ni) bf[ni] = *(h8*)&Bs[wn * 64 + ni * 16 + l15][q * 8];
        #pragma unroll
        for (int mi = 0; mi < 4; ++mi)
            #pragma unroll
            for (int ni = 0; ni < 4; ++ni)
                acc[mi][ni] = __builtin_amdgcn_mfma_f32_16x16x32_f16(af[mi], bf[ni], acc[mi][ni], 0, 0, 0);
    }

    if (OUT == 0) {
        float* Cz = (float*)P.C[s] + (long long)(z / P.divC[s]) * P.sChi[s] + (long long)(z % P.divC[s]) * P.sClo[s];
        #pragma unroll
        for (int mi = 0; mi < 4; ++mi)
            #pragma unroll
            for (int r = 0; r < 4; ++r) {
                const int row = m0 + wm * 64 + mi * 16 + q * 4 + r;
                if (row < Mlim) {
                    #pragma unroll
                    for (int ni = 0; ni < 4; ++ni) {
                        const int col = n0 + wn * 64 + ni * 16 + l15;
                        if (col < Nlim) Cz[(long long)row * ldc + col] = acc[mi][ni][r] * alpha;
                    }
                }
            }
    } else {
        half_t* Cz = (half_t*)P.C[s] + (long long)(z / P.divC[s]) * P.sChi[s] + (long long)(z % P.divC[s]) * P.sClo[s];
        #pragma unroll
        for (int mi = 0; mi < 4; ++mi)
            #pragma unroll
            for (int r = 0; r < 4; ++r) {
                const int row = m0 + wm * 64 + mi * 16 + q * 4 + r;
                if (row < Mlim) {
                    #pragma unroll
                    for (int ni = 0; ni < 4; ++ni) {
                        const int col = n0 + wn * 64 + ni * 16 + l15;
                        if (col < Nlim) Cz[(long long)row * ldc + col] = (half_t)(acc[mi][ni][r] * alpha);
                    }
                }
            }
    }

    if (STATS) {
        float sv = 0.f, qq = 0.f;
        #pragma unroll
        for (int mi = 0; mi < 4; ++mi)
            #pragma unroll
            for (int ni = 0; ni < 4; ++ni)
                #pragma unroll
                for (int r = 0; r < 4; ++r) {
                    const float v = acc[mi][ni][r] * alpha;   // masked entries are exact 0
                    sv += v; qq += v * v;
                }
        #pragma unroll
        for (int o = 32; o > 0; o >>= 1) {
            sv += __shfl_down(sv, o, 64);
            qq += __shfl_down(qq, o, 64);
        }
        if (lane == 0) { red[wv] = sv; red[4 + wv] = qq; }
        __syncthreads();
        if (tid == 0) {
            const int pidx = nt * mTl + mt;
            float* PO = P.Part[s] + (long long)z * 240;
            PO[pidx * 2 + 0] = red[0] + red[1] + red[2] + red[3];
            PO[pidx * 2 + 1] = red[4] + red[5] + red[6] + red[7];
        }
    }
}

// ---------------- batched row softmax (fp16 in/out, in place), block = 128, 1 row ----------------
struct SMArgs {
    half_t* buf[4];
    const float* part[4];
    int cumRows[3];
    int lg2c[4];
    int nPart[4];
    float pinv[4];
};

__global__ __launch_bounds__(128) void softmax_b(SMArgs a)
{
    int r = blockIdx.x;
    int s = 0, basev = 0;
    #pragma unroll
    for (int i = 0; i < 3; ++i) if (r >= a.cumRows[i]) { s = i + 1; basev = a.cumRows[i]; }
    r -= basev;
    const int z = r >> a.lg2c[s];
    const int tid = threadIdx.x;

    const float* part = a.part[s] + (long long)z * 240;
    float S = 0.f, Q = 0.f;
    if (tid < a.nPart[s]) { S = part[tid * 2]; Q = part[tid * 2 + 1]; }
    #pragma unroll
    for (int o = 32; o > 0; o >>= 1) {
        S += __shfl_down(S, o, 64);
        Q += __shfl_down(Q, o, 64);
    }
    __shared__ float sred[4];
    if ((tid & 63) == 0) { sred[tid >> 6] = S; sred[2 + (tid >> 6)] = Q; }
    __syncthreads();
    __shared__ float s_rs;
    if (tid == 0) {
        const float Ss = sred[0] + sred[1], Qs = sred[2] + sred[3];
        const float m = Ss * a.pinv[s];
        s_rs = rsqrtf(fmaxf(Qs * a.pinv[s] - m * m, 0.f) + 1e-5f);
    }
    __syncthreads();
    const float rs = s_rs;

    half_t* p = a.buf[s] + (long long)r * 960;
    const bool act = tid < 120;
    float loc[8];
    float mx = -1e30f;
    if (act) {
        h8 v = *(h8*)(p + tid * 8);
        #pragma unroll
        for (int e = 0; e < 8; ++e) { loc[e] = (float)v[e] * rs; mx = fmaxf(mx, loc[e]); }
    }
    #pragma unroll
    for (int o = 32; o > 0; o >>= 1) mx = fmaxf(mx, __shfl_down(mx, o, 64));
    __shared__ float sm2[2];
    if ((tid & 63) == 0) sm2[tid >> 6] = mx;
    __syncthreads();
    mx = fmaxf(sm2[0], sm2[1]);

    float sum = 0.f;
    if (act) {
        #pragma unroll
        for (int e = 0; e < 8; ++e) { loc[e] = __expf(loc[e] - mx); sum += loc[e]; }
    }
    #pragma unroll
    for (int o = 32; o > 0; o >>= 1) sum += __shfl_down(sum, o, 64);
    __shared__ float ss2[2];
    if ((tid & 63) == 0) ss2[tid >> 6] = sum;
    __syncthreads();
    const float inv = 1.0f / (ss2[0] + ss2[1]);
    if (act) {
        h8 o8;
        #pragma unroll
        for (int e = 0; e < 8; ++e) o8[e] = (half_t)(loc[e] * inv);
        *(h8*)(p + tid * 8) = o8;
    }
}

// ---------------- launcher ----------------
extern "C" void kernel_launch(void* const* d_in, const int* in_sizes, int n_in,
                              void* d_out, int out_size, void* d_ws, size_t ws_size,
                              hipStream_t stream)
{
    const float* emb[4]  = {(const float*)d_in[0], (const float*)d_in[1],
                            (const float*)d_in[2], (const float*)d_in[3]};
    const float* emb_all = (const float*)d_in[4];
    const float* Wq[4]   = {(const float*)d_in[5], (const float*)d_in[7],
                            (const float*)d_in[9], (const float*)d_in[11]};
    const float* Wo[4]   = {(const float*)d_in[6], (const float*)d_in[8],
                            (const float*)d_in[10], (const float*)d_in[12]};
    const float* Wk = (const float*)d_in[13];
    const float* Wv = (const float*)d_in[14];
    float* out = (float*)d_out;

    // workspace (half elements), ~250 MB
    half_t* hb = (half_t*)d_ws;
    half_t* EAh = hb;                              // 3010560
    half_t* Eh  = EAh + 3010560;                   // 3010560
    half_t* Wkh = Eh  + 3010560;                   // 3686400
    half_t* Wvh = Wkh + 3686400;                   // 3686400
    half_t* Wqh = Wvh + 3686400;                   // 1392640
    half_t* Wo4 = Wqh + 1392640;                   // 1392640
    half_t* KT  = Wo4 + 1392640;                   // [h][b][960][208]      = 12779520
    half_t* Vh  = KT  + 12779520;                  // [h][3136][960]        = 12042240
    half_t* QtT = Vh  + 12042240;                  // per-scale [64][ch][208] = 12779520
    half_t* Ctx = QtT + 12779520;                  // per-scale [16][196][4ch] = 12042240
    half_t* Sch = Ctx + 12042240;                  // per-scale [64][ch][960]  = 58982400
    float*  Part = (float*)(Sch + 58982400);       // 4 * 64 * 240 floats

    const int  chs[4]   = {64, 128, 256, 512};
    const int  lg2c[4]  = {6, 7, 8, 9};
    const long long offE[4]   = {0, 200704, 602112, 1404928};      // 3136*ch prefix
    const long long offQ[4]   = {0, 16384, 81920, 344064};         // 4*ch*ch prefix
    const long long offQt[4]  = {0, 851968, 2555904, 5963776};     // 64*208*ch prefix
    const long long offSc[4]  = {0, 3932160, 11796480, 27525120};  // 64*960*ch prefix
    const long long offCtx[4] = {0, 802816, 2408448, 5619712};     // 16*196*4ch prefix
    const long long ooff[4]   = {0, 200704, 602112, 1404928};
    const float inv_sqrt_kv = 0.03227486121839514f;

    // ---- prep: 15 segments (11 casts + 4 Wo replications) ----
    PrepArgs pa;
    pa.src[0] = emb_all; pa.dst[0] = EAh; pa.n[0] = 3010560; pa.mode[0] = 0; pa.lg2[0] = 0;
    for (int i = 0; i < 4; ++i) {
        pa.src[1 + i] = emb[i]; pa.dst[1 + i] = Eh + offE[i];
        pa.n[1 + i] = (int)(3136LL * chs[i]); pa.mode[1 + i] = 0; pa.lg2[1 + i] = 0;
    }
    pa.src[5] = Wk; pa.dst[5] = Wkh; pa.n[5] = 3686400; pa.mode[5] = 0; pa.lg2[5] = 0;
    pa.src[6] = Wv; pa.dst[6] = Wvh; pa.n[6] = 3686400; pa.mode[6] = 0; pa.lg2[6] = 0;
    for (int i = 0; i < 4; ++i) {
        pa.src[7 + i] = Wq[i]; pa.dst[7 + i] = Wqh + offQ[i];
        pa.n[7 + i] = 4 * chs[i] * chs[i]; pa.mode[7 + i] = 0; pa.lg2[7 + i] = 0;
        pa.src[11 + i] = Wo[i]; pa.dst[11 + i] = Wo4 + offQ[i];
        pa.n[11 + i] = chs[i] * chs[i]; pa.mode[11 + i] = 1; pa.lg2[11 + i] = lg2c[i];
    }
    prep_k<<<dim3(1800, 15), 256, 0, stream>>>(pa);

    // ---- K projection (transposed -> KT[h][b][j][n208]), z = h, 64x64 kernel ----
    {
        BP p{};
        p.A[0] = EAh; p.B[0] = Wkh; p.C[0] = KT; p.Part[0] = nullptr;
        p.Mlim[0] = 3136; p.Nlim[0] = 960; p.Klim[0] = 960; p.nKt[0] = 30;
        p.lda[0] = 960; p.ldb[0] = 960; p.ldc[0] = 208;
        p.divA[0] = 1; p.sAhi[0] = 0; p.sAlo[0] = 0;
        p.divB[0] = 1; p.sBhi[0] = 921600; p.sBlo[0] = 0;
        p.divC[0] = 1; p.sChi[0] = 3194880; p.sClo[0] = 0;
        p.tStrB[0] = 199680; p.tComp[0] = 1; p.alpha[0] = 1.0f;
        p.mT[0] = 49; p.nT[0] = 15;
        p.cumEnd[0] = p.cumEnd[1] = p.cumEnd[2] = 2940;
        p.totW = 2940;
        gemm_b<2, false><<<2940, 128, 0, stream>>>(p);
    }
    // ---- V projection (normal -> Vh[h][3136][960]), z = h, 128x128 kernel ----
    {
        BP p{};
        p.A[0] = EAh; p.B[0] = Wvh; p.C[0] = Vh; p.Part[0] = nullptr;
        p.Mlim[0] = 3136; p.Nlim[0] = 960; p.Klim[0] = 960; p.nKt[0] = 30;
        p.lda[0] = 960; p.ldb[0] = 960; p.ldc[0] = 960;
        p.divA[0] = 1; p.sAhi[0] = 0; p.sAlo[0] = 0;
        p.divB[0] = 1; p.sBhi[0] = 921600; p.sBlo[0] = 0;
        p.divC[0] = 1; p.sChi[0] = 3010560; p.sClo[0] = 0;
        p.alpha[0] = 1.0f;
        p.mT[0] = 25; p.nT[0] = 8;
        p.cumEnd[0] = p.cumEnd[1] = p.cumEnd[2] = 800;
        p.totW = 800;
        gemm_w<1, false><<<800, 256, 0, stream>>>(p);
    }

    // ---- Q-proj, all scales: QtT[z=4b+h][d][n208] (transpose, 64x64 kernel) ----
    {
        BP p{};
        int cum = 0;
        for (int s = 0; s < 4; ++s) {
            const int ch = chs[s];
            p.A[s] = Eh + offE[s]; p.B[s] = Wqh + offQ[s]; p.C[s] = QtT + offQt[s]; p.Part[s] = nullptr;
            p.Mlim[s] = 196; p.Nlim[s] = ch; p.Klim[s] = ch; p.nKt[s] = ch / 32;
            p.lda[s] = ch; p.ldb[s] = ch; p.ldc[s] = 208;
            p.divA[s] = 4; p.sAhi[s] = 196LL * ch; p.sAlo[s] = 0;
            p.divB[s] = 4; p.sBhi[s] = 0; p.sBlo[s] = (long long)ch * ch;
            p.divC[s] = 1; p.sChi[s] = 208LL * ch; p.sClo[s] = 0;
            p.tStrB[s] = 0; p.tComp[s] = 0; p.alpha[s] = 1.0f;
            p.mT[s] = 4; p.nT[s] = ch / 64;
            cum += 4 * (ch / 64) * 64;
            if (s < 3) p.cumEnd[s] = cum;
        }
        p.totW = 3840;
        gemm_b<2, false><<<3840, 128, 0, stream>>>(p);
    }

    // ---- Scores, all scales: Sch[z][d][960] fp16 + fused stat partials (128x128) ----
    {
        BP p{};
        int cum = 0;
        for (int s = 0; s < 4; ++s) {
            const int ch = chs[s];
            p.A[s] = QtT + offQt[s]; p.B[s] = KT; p.C[s] = Sch + offSc[s];
            p.Part[s] = Part + (long long)s * 64 * 240;
            p.Mlim[s] = ch; p.Nlim[s] = 960; p.Klim[s] = 196; p.nKt[s] = 7;
            p.lda[s] = 208; p.ldb[s] = 208; p.ldc[s] = 960;
            p.divA[s] = 1; p.sAhi[s] = 208LL * ch; p.sAlo[s] = 0;
            p.divB[s] = 4; p.sBhi[s] = 199680; p.sBlo[s] = 3194880;
            p.divC[s] = 1; p.sChi[s] = 960LL * ch; p.sClo[s] = 0;
            p.alpha[s] = inv_sqrt_kv;
            p.mT[s] = (ch + 127) / 128; p.nT[s] = 8;
            cum += p.mT[s] * 8 * 64;
            if (s < 3) p.cumEnd[s] = cum;
        }
        p.totW = 4096;
        gemm_w<1, true><<<4096, 256, 0, stream>>>(p);
    }

    // ---- softmax, all scales (in place fp16) ----
    {
        SMArgs sa;
        int cum = 0;
        for (int s = 0; s < 4; ++s) {
            const int ch = chs[s];
            sa.buf[s] = Sch + offSc[s];
            sa.part[s] = Part + (long long)s * 64 * 240;
            sa.lg2c[s] = lg2c[s];
            sa.nPart[s] = ((ch + 127) / 128) * 8;
            sa.pinv[s] = 1.0f / (ch * 960);
            cum += 64 * ch;
            if (s < 3) sa.cumRows[s] = cum;
        }
        softmax_b<<<61440, 128, 0, stream>>>(sa);
    }

    // ---- per-head ctx, all scales: Ctx[b][n][h*ch+d] = 0.25 * sum_j V * P (128x128) ----
    {
        BP p{};
        int cum = 0;
        for (int s = 0; s < 4; ++s) {
            const int ch = chs[s];
            p.A[s] = Vh; p.B[s] = Sch + offSc[s]; p.C[s] = Ctx + offCtx[s]; p.Part[s] = nullptr;
            p.Mlim[s] = 196; p.Nlim[s] = ch; p.Klim[s] = 960; p.nKt[s] = 30;
            p.lda[s] = 960; p.ldb[s] = 960; p.ldc[s] = 4 * ch;
            p.divA[s] = 4; p.sAhi[s] = 188160; p.sAlo[s] = 3010560;
            p.divB[s] = 1; p.sBhi[s] = 960LL * ch; p.sBlo[s] = 0;
            p.divC[s] = 4; p.sChi[s] = 784LL * ch; p.sClo[s] = ch;
            p.alpha[s] = 0.25f;
            p.mT[s] = 2; p.nT[s] = (ch + 127) / 128;
            cum += 2 * p.nT[s] * 64;
            if (s < 3) p.cumEnd[s] = cum;
        }
        p.totW = 1024;
        gemm_w<1, false><<<1024, 256, 0, stream>>>(p);
    }

    // ---- out-proj, all scales: out[b][n][e] fp32 = Ctx (196 x 4ch) x Wo4^T (64x64) ----
    {
        BP p{};
        int cum = 0;
        for (int s = 0; s < 4; ++s) {
            const int ch = chs[s];
            p.A[s] = Ctx + offCtx[s]; p.B[s] = Wo4 + offQ[s]; p.C[s] = out + ooff[s]; p.Part[s] = nullptr;
            p.Mlim[s] = 196; p.Nlim[s] = ch; p.Klim[s] = 4 * ch; p.nKt[s] = ch / 8;
            p.lda[s] = 4 * ch; p.ldb[s] = 4 * ch; p.ldc[s] = ch;
            p.divA[s] = 1; p.sAhi[s] = 784LL * ch; p.sAlo[s] = 0;
            p.divB[s] = 1; p.sBhi[s] = 0; p.sBlo[s] = 0;
            p.divC[s] = 1; p.sChi[s] = 196LL * ch; p.sClo[s] = 0;
            p.tStrB[s] = 0; p.tComp[s] = 0; p.alpha[s] = 1.0f;
            p.mT[s] = 4; p.nT[s] = ch / 64;
            cum += 4 * (ch / 64) * 16;
            if (s < 3) p.cumEnd[s] = cum;
        }
        p.totW = 960;
        gemm_b<0, false><<<960, 128, 0, stream>>>(p);
    }
}

// Round 7
// 452.714 us; speedup vs baseline: 5.7924x; 1.1819x over previous
//
#include <hip/hip_runtime.h>

typedef _Float16 half_t;
typedef _Float16 h8 __attribute__((ext_vector_type(8)));
typedef _Float16 h4 __attribute__((ext_vector_type(4)));
typedef float f4v __attribute__((ext_vector_type(4)));

__device__ __forceinline__ int div196(int m) { return (m * 21400) >> 22; }  // exact for m<=3135

// ---------------- prep: cast fp32->fp16 (mode 0) or cast+replicate-4 (mode 1) ----------------
struct PrepArgs {
    const float* src[15];
    half_t* dst[15];
    int n[15];
    int mode[15];
    int lg2[15];
};

__global__ __launch_bounds__(256) void prep_k(PrepArgs a)
{
    const int seg = blockIdx.y;
    const int i8 = (blockIdx.x * 256 + threadIdx.x) * 8;
    if (i8 >= a.n[seg]) return;
    const float* s = a.src[seg] + i8;
    f4v v0 = *(const f4v*)s;
    f4v v1 = *(const f4v*)(s + 4);
    h8 o;
    o[0] = (half_t)v0[0]; o[1] = (half_t)v0[1]; o[2] = (half_t)v0[2]; o[3] = (half_t)v0[3];
    o[4] = (half_t)v1[0]; o[5] = (half_t)v1[1]; o[6] = (half_t)v1[2]; o[7] = (half_t)v1[3];
    if (a.mode[seg] == 0) {
        *(h8*)(a.dst[seg] + i8) = o;
    } else {
        const int lg = a.lg2[seg], ch = 1 << lg;
        const int e = i8 >> lg, d = i8 & (ch - 1);
        half_t* base = a.dst[seg] + ((long long)e << (lg + 2)) + d;
        #pragma unroll
        for (int r = 0; r < 4; ++r) *(h8*)(base + r * ch) = o;
    }
}

// ---------------- staged tile load with row/k-limit masking ----------------
__device__ __forceinline__ h8 ldtile(const half_t* __restrict__ base, int row, int kb,
                                     int ld, int rowLim, int Klim)
{
    h8 v = {0, 0, 0, 0, 0, 0, 0, 0};
    if (row >= rowLim) return v;
    const half_t* p = base + (long long)row * ld + kb;
    if (kb + 8 <= Klim) return *(const h8*)p;
    #pragma unroll
    for (int e = 0; e < 8; ++e) if (kb + e < Klim) v[e] = p[e];
    return v;
}

// ---------------- batch descriptor for up to 4 heterogeneous "scales" ----------------
struct BP {
    const half_t* A[4]; const half_t* B[4]; void* C[4];
    int Mlim[4], Nlim[4], Klim[4], nKt[4], lda[4], ldb[4], ldc[4];
    int divA[4]; long long sAhi[4], sAlo[4];
    int divB[4]; long long sBhi[4], sBlo[4];
    int divC[4]; long long sChi[4], sClo[4];
    long long tStrB[4]; int tComp[4];
    float alpha[4];
    int mT[4], nT[4];
    int cumEnd[3];
    int totW;
};

// ---------------- 64x64 MFMA GEMM (2 waves) — Q-proj (transpose out) & out-proj ----------------
template<int OUT>
__global__ __launch_bounds__(128)
void gemm_b(BP P)
{
    __shared__ __align__(16) half_t SM[64 * 72];
    half_t (*As)[32] = (half_t(*)[32])SM;
    half_t (*Bs)[32] = (half_t(*)[32])(SM + 2048);

    int b = blockIdx.x;
    int s = 0, basev = 0;
    #pragma unroll
    for (int i = 0; i < 3; ++i) if (b >= P.cumEnd[i]) { s = i + 1; basev = P.cumEnd[i]; }
    b -= basev;
    const int mTl = P.mT[s], nTl = P.nT[s];
    const int mt = b % mTl;
    const int t2 = b / mTl;
    const int nt = t2 % nTl;
    const int z  = t2 / nTl;

    const half_t* A  = P.A[s] + (long long)(z / P.divA[s]) * P.sAhi[s] + (long long)(z % P.divA[s]) * P.sAlo[s];
    const half_t* Bp = P.B[s] + (long long)(z / P.divB[s]) * P.sBhi[s] + (long long)(z % P.divB[s]) * P.sBlo[s];
    const int Mlim = P.Mlim[s], Klim = P.Klim[s], nKt = P.nKt[s];
    const int lda = P.lda[s], ldb = P.ldb[s], ldc = P.ldc[s];
    const float alpha = P.alpha[s];
    const int m0 = mt * 64, n0 = nt * 64;
    const int tid = threadIdx.x;
    const int lane = tid & 63, w = tid >> 6;
    const int l15 = lane & 15, q = lane >> 4;

    const int r0 = tid >> 2, kg = tid & 3;
    const int r1 = r0 + 32;

    f4v acc[4][2];
    #pragma unroll
    for (int i = 0; i < 4; ++i)
        #pragma unroll
        for (int j = 0; j < 2; ++j) acc[i][j] = (f4v){0.f, 0.f, 0.f, 0.f};

    for (int kt = 0; kt < nKt; ++kt) {
        const int kb = kt * 32 + kg * 8;
        h8 a0 = ldtile(A, m0 + r0, kb, lda, Mlim, Klim);
        h8 a1 = ldtile(A, m0 + r1, kb, lda, Mlim, Klim);
        h8 b0 = ldtile(Bp, n0 + r0, kb, ldb, 1 << 30, Klim);
        h8 b1 = ldtile(Bp, n0 + r1, kb, ldb, 1 << 30, Klim);
        __syncthreads();
        *(h8*)&As[r0][kg * 8] = a0;
        *(h8*)&As[r1][kg * 8] = a1;
        *(h8*)&Bs[r0][kg * 8] = b0;
        *(h8*)&Bs[r1][kg * 8] = b1;
        __syncthreads();
        h8 af[4], bf[2];
        #pragma unroll
        for (int mti = 0; mti < 4; ++mti) af[mti] = *(h8*)&As[mti * 16 + l15][q * 8];
        #pragma unroll
        for (int nti = 0; nti < 2; ++nti) bf[nti] = *(h8*)&Bs[w * 32 + nti * 16 + l15][q * 8];
        #pragma unroll
        for (int mti = 0; mti < 4; ++mti)
            #pragma unroll
            for (int nti = 0; nti < 2; ++nti)
                acc[mti][nti] = __builtin_amdgcn_mfma_f32_16x16x32_f16(af[mti], bf[nti], acc[mti][nti], 0, 0, 0);
    }

    if (OUT == 0) {
        float* Cz = (float*)P.C[s] + (long long)(z / P.divC[s]) * P.sChi[s] + (long long)(z % P.divC[s]) * P.sClo[s];
        #pragma unroll
        for (int mti = 0; mti < 4; ++mti)
            #pragma unroll
            for (int r = 0; r < 4; ++r) {
                const int row = m0 + mti * 16 + q * 4 + r;
                if (row < Mlim) {
                    #pragma unroll
                    for (int nti = 0; nti < 2; ++nti) {
                        const int col = n0 + w * 32 + nti * 16 + l15;
                        Cz[(long long)row * ldc + col] = acc[mti][nti][r] * alpha;
                    }
                }
            }
    } else {
        __syncthreads();
        half_t (*Tt)[72] = (half_t(*)[72])SM;
        #pragma unroll
        for (int mti = 0; mti < 4; ++mti)
            #pragma unroll
            for (int nti = 0; nti < 2; ++nti) {
                h4 pk;
                #pragma unroll
                for (int r = 0; r < 4; ++r) pk[r] = (half_t)(acc[mti][nti][r] * alpha);
                *(h4*)&Tt[w * 32 + nti * 16 + l15][mti * 16 + q * 4] = pk;
            }
        __syncthreads();
        half_t* Cz = (half_t*)P.C[s] + (long long)(z / P.divC[s]) * P.sChi[s] + (long long)(z % P.divC[s]) * P.sClo[s];
        const long long tStrB = P.tStrB[s];
        const int jl = tid >> 1, mh = (tid & 1) * 32;
        #pragma unroll
        for (int g = 0; g < 4; ++g) {
            const int ml = mh + g * 8;
            const int mg = m0 + ml;
            h8 v = *(h8*)&Tt[jl][ml];
            if (P.tComp[s]) {
                const int b0 = div196(mg), b1 = div196(mg + 7);
                if (b0 == b1 && mg + 8 <= Mlim) {
                    half_t* rp = Cz + (long long)b0 * tStrB + (long long)(n0 + jl) * ldc + (mg - 196 * b0);
                    h4 lo = {v[0], v[1], v[2], v[3]};
                    h4 hi = {v[4], v[5], v[6], v[7]};
                    *(h4*)rp = lo;
                    *(h4*)(rp + 4) = hi;
                } else {
                    #pragma unroll
                    for (int e = 0; e < 8; ++e) {
                        const int m = mg + e;
                        if (m < Mlim) {
                            const int bb = div196(m);
                            Cz[(long long)bb * tStrB + (long long)(n0 + jl) * ldc + (m - 196 * bb)] = v[e];
                        }
                    }
                }
            } else {
                if (mg + 8 <= Mlim) {
                    *(h8*)(Cz + (long long)(n0 + jl) * ldc + mg) = v;
                } else {
                    #pragma unroll
                    for (int e = 0; e < 8; ++e)
                        if (mg + e < Mlim) Cz[(long long)(n0 + jl) * ldc + mg + e] = v[e];
                }
            }
        }
    }
}

// ---------------- 128x128 MFMA GEMM (256 threads) — K-proj (OUT=2) / V-proj (OUT=1) ----------------
template<int OUT>
__global__ __launch_bounds__(256)
void gemm_w(BP P)
{
    __shared__ __align__(16) half_t SMEM[128 * 80];     // As[128][40] + Bs[128][40]; Tt overlay
    half_t (*As)[40] = (half_t(*)[40])SMEM;
    half_t (*Bs)[40] = (half_t(*)[40])(SMEM + 128 * 40);

    const int per = gridDim.x >> 3;
    int wk = (blockIdx.x & 7) * per + (blockIdx.x >> 3);
    if (wk >= P.totW) return;
    int s = 0, basev = 0;
    #pragma unroll
    for (int i = 0; i < 3; ++i) if (wk >= P.cumEnd[i]) { s = i + 1; basev = P.cumEnd[i]; }
    wk -= basev;
    const int mTl = P.mT[s], nTl = P.nT[s];
    const int mt = wk % mTl;
    const int t2 = wk / mTl;
    const int nt = t2 % nTl;
    const int z  = t2 / nTl;

    const half_t* A  = P.A[s] + (long long)(z / P.divA[s]) * P.sAhi[s] + (long long)(z % P.divA[s]) * P.sAlo[s];
    const half_t* Bp = P.B[s] + (long long)(z / P.divB[s]) * P.sBhi[s] + (long long)(z % P.divB[s]) * P.sBlo[s];
    const int Mlim = P.Mlim[s], Nlim = P.Nlim[s], Klim = P.Klim[s], nKt = P.nKt[s];
    const int lda = P.lda[s], ldb = P.ldb[s], ldc = P.ldc[s];
    const float alpha = P.alpha[s];
    const int m0 = mt * 128, n0 = nt * 128;
    const int tid = threadIdx.x;
    const int lane = tid & 63, wv = tid >> 6;
    const int wm = wv & 1, wn = wv >> 1;
    const int l15 = lane & 15, q = lane >> 4;

    const int r0 = tid >> 2, kg = tid & 3;

    f4v acc[4][4];
    #pragma unroll
    for (int i = 0; i < 4; ++i)
        #pragma unroll
        for (int j = 0; j < 4; ++j) acc[i][j] = (f4v){0.f, 0.f, 0.f, 0.f};

    for (int kt = 0; kt < nKt; ++kt) {
        const int kb = kt * 32 + kg * 8;
        h8 a0 = ldtile(A, m0 + r0, kb, lda, Mlim, Klim);
        h8 a1 = ldtile(A, m0 + r0 + 64, kb, lda, Mlim, Klim);
        h8 b0 = ldtile(Bp, n0 + r0, kb, ldb, Nlim, Klim);
        h8 b1 = ldtile(Bp, n0 + r0 + 64, kb, ldb, Nlim, Klim);
        __syncthreads();
        *(h8*)&As[r0][kg * 8] = a0;
        *(h8*)&As[r0 + 64][kg * 8] = a1;
        *(h8*)&Bs[r0][kg * 8] = b0;
        *(h8*)&Bs[r0 + 64][kg * 8] = b1;
        __syncthreads();
        h8 af[4], bf[4];
        #pragma unroll
        for (int mi = 0; mi < 4; ++mi) af[mi] = *(h8*)&As[wm * 64 + mi * 16 + l15][q * 8];
        #pragma unroll
        for (int ni = 0; ni < 4; ++ni) bf[ni] = *(h8*)&Bs[wn * 64 + ni * 16 + l15][q * 8];
        #pragma unroll
        for (int mi = 0; mi < 4; ++mi)
            #pragma unroll
            for (int ni = 0; ni < 4; ++ni)
                acc[mi][ni] = __builtin_amdgcn_mfma_f32_16x16x32_f16(af[mi], bf[ni], acc[mi][ni], 0, 0, 0);
    }

    if (OUT == 1) {
        half_t* Cz = (half_t*)P.C[s] + (long long)(z / P.divC[s]) * P.sChi[s] + (long long)(z % P.divC[s]) * P.sClo[s];
        #pragma unroll
        for (int mi = 0; mi < 4; ++mi)
            #pragma unroll
            for (int r = 0; r < 4; ++r) {
                const int row = m0 + wm * 64 + mi * 16 + q * 4 + r;
                if (row < Mlim) {
                    #pragma unroll
                    for (int ni = 0; ni < 4; ++ni) {
                        const int col = n0 + wn * 64 + ni * 16 + l15;
                        if (col < Nlim) Cz[(long long)row * ldc + col] = (half_t)(acc[mi][ni][r] * alpha);
                    }
                }
            }
    } else {
        // transpose epilogue, two half-passes through LDS overlay.
        // NOTE: rows mg >= Mlim must NOT be written (25*128=3200 > 3136 for K-proj):
        // div196 of an out-of-range row walks into the next head's plane.
        half_t (*Tt)[72] = (half_t(*)[72])SMEM;   // 128 x 72 halves <= SMEM
        half_t* Cz = (half_t*)P.C[s] + (long long)(z / P.divC[s]) * P.sChi[s] + (long long)(z % P.divC[s]) * P.sClo[s];
        const long long tStrB = P.tStrB[s];
        const int jl = tid >> 1, mh = (tid & 1) * 32;
        #pragma unroll
        for (int p = 0; p < 2; ++p) {
            __syncthreads();
            if (wm == p) {
                #pragma unroll
                for (int mi = 0; mi < 4; ++mi)
                    #pragma unroll
                    for (int ni = 0; ni < 4; ++ni) {
                        h4 pk;
                        #pragma unroll
                        for (int r = 0; r < 4; ++r) pk[r] = (half_t)(acc[mi][ni][r] * alpha);
                        *(h4*)&Tt[wn * 64 + ni * 16 + l15][mi * 16 + q * 4] = pk;
                    }
            }
            __syncthreads();
            const int n = n0 + jl;
            if (n < Nlim) {
                #pragma unroll
                for (int g = 0; g < 4; ++g) {
                    const int ml = mh + g * 8;
                    const int mg = m0 + p * 64 + ml;
                    h8 v = *(h8*)&Tt[jl][ml];
                    const int b0 = div196(mg), b1 = div196(mg + 7);
                    if (b0 == b1 && mg + 8 <= Mlim) {
                        half_t* rp = Cz + (long long)b0 * tStrB + (long long)n * ldc + (mg - 196 * b0);
                        h4 lo = {v[0], v[1], v[2], v[3]};
                        h4 hi = {v[4], v[5], v[6], v[7]};
                        *(h4*)rp = lo;
                        *(h4*)(rp + 4) = hi;
                    } else {
                        #pragma unroll
                        for (int e = 0; e < 8; ++e) {
                            const int m = mg + e;
                            if (m < Mlim) {
                                const int bb = div196(m);
                                Cz[(long long)bb * tStrB + (long long)n * ldc + (m - 196 * bb)] = v[e];
                            }
                        }
                    }
                }
            }
        }
    }
}

// ---------------- scores: A-strip-resident GEMM + fused IN-stat partials ----------------
// One block: 128-row Q-strip (d-dim) x full N=960 (j-dim) for one z. Raw fp16 scores out.
struct ScP {
    const half_t* Qt[4];
    const half_t* KT;
    half_t* C[4];
    float* Part[4];
    int Mlim[4];
    long long sA[4], sC[4];
    float alpha;
};

__global__ __launch_bounds__(256)
void gemm_s(ScP P)
{
    __shared__ __align__(16) half_t As[128][232];   // full-K strip (196 -> 224 used, zero-pad)
    __shared__ __align__(16) half_t Bs[128][72];    // 64-wide B chunk
    __shared__ float red[8];

    const int per = gridDim.x >> 3;                 // 512/8 = 64 -> 8 z per XCD
    int wk = (blockIdx.x & 7) * per + (blockIdx.x >> 3);
    const int z = wk >> 3, r = wk & 7;
    int s, mt;
    if (r < 1)      { s = 0; mt = 0; }
    else if (r < 2) { s = 1; mt = 0; }
    else if (r < 4) { s = 2; mt = r - 2; }
    else            { s = 3; mt = r - 4; }
    const int b = z >> 2, h = z & 3;

    const half_t* A = P.Qt[s] + (long long)z * P.sA[s] + (long long)mt * 128 * 208;
    const half_t* B = P.KT + (long long)h * 3194880 + (long long)b * 199680;
    const int rowLim = P.Mlim[s] - mt * 128;        // rows valid in this strip
    const float alpha = P.alpha;

    const int tid = threadIdx.x;
    const int lane = tid & 63, wv = tid >> 6;
    const int wm = wv & 1, wn = wv >> 1;
    const int l15 = lane & 15, q = lane >> 4;
    const int r0 = tid >> 2, kg = tid & 3;

    // stage A strip (reads covered by the first barrier inside the nt loop)
    #pragma unroll
    for (int c = 0; c < 7; ++c) {
        const int kb = c * 32 + kg * 8;
        h8 a0 = ldtile(A, r0, kb, 208, rowLim, 196);
        h8 a1 = ldtile(A, r0 + 64, kb, 208, rowLim, 196);
        *(h8*)&As[r0][kb] = a0;
        *(h8*)&As[r0 + 64][kb] = a1;
    }

    half_t* Cz = P.C[s] + (long long)z * P.sC[s] + (long long)mt * 128 * 960;
    float sv = 0.f, qq = 0.f;

    for (int nt = 0; nt < 8; ++nt) {
        f4v acc[4][4];
        #pragma unroll
        for (int i = 0; i < 4; ++i)
            #pragma unroll
            for (int j = 0; j < 4; ++j) acc[i][j] = (f4v){0.f, 0.f, 0.f, 0.f};

        const int j0 = nt * 128;
        #pragma unroll
        for (int c2 = 0; c2 < 4; ++c2) {
            h8 b00 = ldtile(B, j0 + r0,      c2 * 64 + kg * 8,      208, 960, 196);
            h8 b01 = ldtile(B, j0 + r0,      c2 * 64 + 32 + kg * 8, 208, 960, 196);
            h8 b10 = ldtile(B, j0 + r0 + 64, c2 * 64 + kg * 8,      208, 960, 196);
            h8 b11 = ldtile(B, j0 + r0 + 64, c2 * 64 + 32 + kg * 8, 208, 960, 196);
            __syncthreads();
            *(h8*)&Bs[r0][kg * 8] = b00;
            *(h8*)&Bs[r0][32 + kg * 8] = b01;
            *(h8*)&Bs[r0 + 64][kg * 8] = b10;
            *(h8*)&Bs[r0 + 64][32 + kg * 8] = b11;
            __syncthreads();
            const int nkk = (c2 < 3) ? 2 : 1;
            for (int kk = 0; kk < nkk; ++kk) {
                const int base = c2 * 64 + kk * 32;
                h8 af[4], bf[4];
                #pragma unroll
                for (int mi = 0; mi < 4; ++mi) af[mi] = *(h8*)&As[wm * 64 + mi * 16 + l15][base + q * 8];
                #pragma unroll
                for (int ni = 0; ni < 4; ++ni) bf[ni] = *(h8*)&Bs[wn * 64 + ni * 16 + l15][kk * 32 + q * 8];
                #pragma unroll
                for (int mi = 0; mi < 4; ++mi)
                    #pragma unroll
                    for (int ni = 0; ni < 4; ++ni)
                        acc[mi][ni] = __builtin_amdgcn_mfma_f32_16x16x32_f16(af[mi], bf[ni], acc[mi][ni], 0, 0, 0);
            }
        }
        // epilogue for this n-tile: raw fp16 scores + stat accumulation
        #pragma unroll
        for (int mi = 0; mi < 4; ++mi)
            #pragma unroll
            for (int rr = 0; rr < 4; ++rr) {
                const int rowl = wm * 64 + mi * 16 + q * 4 + rr;
                #pragma unroll
                for (int ni = 0; ni < 4; ++ni) {
                    const int col = j0 + wn * 64 + ni * 16 + l15;
                    const float v = acc[mi][ni][rr] * alpha;   // masked lanes: exact 0
                    sv += v; qq += v * v;
                    if (rowl < rowLim && col < 960)
                        Cz[(long long)rowl * 960 + col] = (half_t)v;
                }
            }
    }

    #pragma unroll
    for (int o = 32; o > 0; o >>= 1) {
        sv += __shfl_down(sv, o, 64);
        qq += __shfl_down(qq, o, 64);
    }
    if (lane == 0) { red[wv] = sv; red[4 + wv] = qq; }
    __syncthreads();
    if (tid == 0) {
        float* PO = P.Part[s] + (long long)z * 240 + mt * 2;
        PO[0] = red[0] + red[1] + red[2] + red[3];
        PO[1] = red[4] + red[5] + red[6] + red[7];
    }
}

// ---------------- ctx: fused IN-scale + exp + PV GEMM + denominator normalize ----------------
struct CtxP {
    const half_t* V;
    const half_t* S[4];
    half_t* C[4];
    const float* Part[4];
    int ch[4];
    int nPart[4];
    float pinv[4];
};

__global__ __launch_bounds__(256)
void ctx_k(CtxP P)
{
    __shared__ __align__(16) half_t As[128][40];
    __shared__ __align__(16) half_t Bs[128][40];
    __shared__ float denomP[128][4];
    __shared__ float denom[128];

    const int per = gridDim.x >> 3;                 // 1024/8 = 128 -> 8 z per XCD
    int wk = (blockIdx.x & 7) * per + (blockIdx.x >> 3);
    const int z = wk >> 4;
    const int r = wk & 15;
    int s, mt, nt;
    if (r < 2)      { s = 0; mt = r;            nt = 0; }
    else if (r < 4) { s = 1; mt = r - 2;        nt = 0; }
    else if (r < 8) { s = 2; mt = (r - 4) >> 1; nt = (r - 4) & 1; }
    else            { s = 3; mt = (r - 8) >> 2; nt = (r - 8) & 3; }
    const int b = z >> 2, h = z & 3;
    const int chS = P.ch[s];

    // rs from fused stat partials
    const float* part = P.Part[s] + (long long)z * 240;
    float Ssum = 0.f, Qsum = 0.f;
    for (int i = 0; i < P.nPart[s]; ++i) { Ssum += part[i * 2]; Qsum += part[i * 2 + 1]; }
    const float mn = Ssum * P.pinv[s];
    const float rs = rsqrtf(fmaxf(Qsum * P.pinv[s] - mn * mn, 0.f) + 1e-5f);

    const half_t* Av  = P.V + (long long)h * 3010560 + (long long)b * 188160;   // [196][960]
    const half_t* Bsc = P.S[s] + (long long)z * 960 * chS;                      // [ch][960] raw
    const int m0 = mt * 128, n0 = nt * 128;

    const int tid = threadIdx.x;
    const int lane = tid & 63, wv = tid >> 6;
    const int wm = wv & 1, wn = wv >> 1;
    const int l15 = lane & 15, q = lane >> 4;
    const int r0 = tid >> 2, kg = tid & 3;
    const int d0 = n0 + r0, d1 = n0 + r0 + 64;

    f4v acc[4][4];
    #pragma unroll
    for (int i = 0; i < 4; ++i)
        #pragma unroll
        for (int j = 0; j < 4; ++j) acc[i][j] = (f4v){0.f, 0.f, 0.f, 0.f};

    float ds0 = 0.f, ds1 = 0.f;

    for (int kt = 0; kt < 30; ++kt) {
        const int kb = kt * 32 + kg * 8;
        h8 a0 = ldtile(Av, m0 + r0, kb, 960, 196, 960);
        h8 a1 = ldtile(Av, m0 + r0 + 64, kb, 960, 196, 960);
        h8 s0 = {0,0,0,0,0,0,0,0}, s1 = {0,0,0,0,0,0,0,0};
        if (d0 < chS) s0 = *(const h8*)(Bsc + (long long)d0 * 960 + kb);
        if (d1 < chS) s1 = *(const h8*)(Bsc + (long long)d1 * 960 + kb);
        __syncthreads();
        h8 e0 = {0,0,0,0,0,0,0,0}, e1 = {0,0,0,0,0,0,0,0};
        if (d0 < chS) {
            #pragma unroll
            for (int e = 0; e < 8; ++e) { float ev = __expf((float)s0[e] * rs); ds0 += ev; e0[e] = (half_t)ev; }
        }
        if (d1 < chS) {
            #pragma unroll
            for (int e = 0; e < 8; ++e) { float ev = __expf((float)s1[e] * rs); ds1 += ev; e1[e] = (half_t)ev; }
        }
        *(h8*)&As[r0][kg * 8] = a0;
        *(h8*)&As[r0 + 64][kg * 8] = a1;
        *(h8*)&Bs[r0][kg * 8] = e0;
        *(h8*)&Bs[r0 + 64][kg * 8] = e1;
        __syncthreads();
        h8 af[4], bf[4];
        #pragma unroll
        for (int mi = 0; mi < 4; ++mi) af[mi] = *(h8*)&As[wm * 64 + mi * 16 + l15][q * 8];
        #pragma unroll
        for (int ni = 0; ni < 4; ++ni) bf[ni] = *(h8*)&Bs[wn * 64 + ni * 16 + l15][q * 8];
        #pragma unroll
        for (int mi = 0; mi < 4; ++mi)
            #pragma unroll
            for (int ni = 0; ni < 4; ++ni)
                acc[mi][ni] = __builtin_amdgcn_mfma_f32_16x16x32_f16(af[mi], bf[ni], acc[mi][ni], 0, 0, 0);
    }

    denomP[r0][kg] = ds0;
    denomP[r0 + 64][kg] = ds1;
    __syncthreads();
    if (tid < 128) denom[tid] = denomP[tid][0] + denomP[tid][1] + denomP[tid][2] + denomP[tid][3];
    __syncthreads();

    half_t* Cz = P.C[s] + (long long)b * 784 * chS + (long long)h * chS;
    const int ldc = 4 * chS;
    #pragma unroll
    for (int ni = 0; ni < 4; ++ni) {
        const int coll = wn * 64 + ni * 16 + l15;
        const int col = n0 + coll;
        if (col < chS) {
            const float sc = 0.25f / denom[coll];
            #pragma unroll
            for (int mi = 0; mi < 4; ++mi)
                #pragma unroll
                for (int rr = 0; rr < 4; ++rr) {
                    const int row = m0 + wm * 64 + mi * 16 + q * 4 + rr;
                    if (row < 196)
                        Cz[(long long)row * ldc + col] = (half_t)(acc[mi][ni][rr] * sc);
                }
        }
    }
}

// ---------------- launcher ----------------
extern "C" void kernel_launch(void* const* d_in, const int* in_sizes, int n_in,
                              void* d_out, int out_size, void* d_ws, size_t ws_size,
                              hipStream_t stream)
{
    const float* emb[4]  = {(const float*)d_in[0], (const float*)d_in[1],
                            (const float*)d_in[2], (const float*)d_in[3]};
    const float* emb_all = (const float*)d_in[4];
    const float* Wq[4]   = {(const float*)d_in[5], (const float*)d_in[7],
                            (const float*)d_in[9], (const float*)d_in[11]};
    const float* Wo[4]   = {(const float*)d_in[6], (const float*)d_in[8],
                            (const float*)d_in[10], (const float*)d_in[12]};
    const float* Wk = (const float*)d_in[13];
    const float* Wv = (const float*)d_in[14];
    float* out = (float*)d_out;

    half_t* hb = (half_t*)d_ws;
    half_t* EAh = hb;                              // 3010560
    half_t* Eh  = EAh + 3010560;                   // 3010560
    half_t* Wkh = Eh  + 3010560;                   // 3686400
    half_t* Wvh = Wkh + 3686400;                   // 3686400
    half_t* Wqh = Wvh + 3686400;                   // 1392640
    half_t* Wo4 = Wqh + 1392640;                   // 1392640
    half_t* KT  = Wo4 + 1392640;                   // [h][b][960][208]      = 12779520
    half_t* Vh  = KT  + 12779520;                  // [h][3136][960]        = 12042240
    half_t* QtT = Vh  + 12042240;                  // per-scale [64][ch][208] = 12779520
    half_t* Ctx = QtT + 12779520;                  // per-scale [16][196][4ch] = 12042240
    half_t* Sch = Ctx + 12042240;                  // per-scale [64][ch][960] raw = 58982400
    float*  Part = (float*)(Sch + 58982400);       // 4 * 64 * 240 floats

    const int  chs[4]   = {64, 128, 256, 512};
    const int  lg2c[4]  = {6, 7, 8, 9};
    const long long offE[4]   = {0, 200704, 602112, 1404928};
    const long long offQ[4]   = {0, 16384, 81920, 344064};
    const long long offQt[4]  = {0, 851968, 2555904, 5963776};
    const long long offSc[4]  = {0, 3932160, 11796480, 27525120};
    const long long offCtx[4] = {0, 802816, 2408448, 5619712};
    const long long ooff[4]   = {0, 200704, 602112, 1404928};
    const float inv_sqrt_kv = 0.03227486121839514f;

    // ---- prep ----
    PrepArgs pa;
    pa.src[0] = emb_all; pa.dst[0] = EAh; pa.n[0] = 3010560; pa.mode[0] = 0; pa.lg2[0] = 0;
    for (int i = 0; i < 4; ++i) {
        pa.src[1 + i] = emb[i]; pa.dst[1 + i] = Eh + offE[i];
        pa.n[1 + i] = (int)(3136LL * chs[i]); pa.mode[1 + i] = 0; pa.lg2[1 + i] = 0;
    }
    pa.src[5] = Wk; pa.dst[5] = Wkh; pa.n[5] = 3686400; pa.mode[5] = 0; pa.lg2[5] = 0;
    pa.src[6] = Wv; pa.dst[6] = Wvh; pa.n[6] = 3686400; pa.mode[6] = 0; pa.lg2[6] = 0;
    for (int i = 0; i < 4; ++i) {
        pa.src[7 + i] = Wq[i]; pa.dst[7 + i] = Wqh + offQ[i];
        pa.n[7 + i] = 4 * chs[i] * chs[i]; pa.mode[7 + i] = 0; pa.lg2[7 + i] = 0;
        pa.src[11 + i] = Wo[i]; pa.dst[11 + i] = Wo4 + offQ[i];
        pa.n[11 + i] = chs[i] * chs[i]; pa.mode[11 + i] = 1; pa.lg2[11 + i] = lg2c[i];
    }
    prep_k<<<dim3(1800, 15), 256, 0, stream>>>(pa);

    // ---- K projection (transposed -> KT[h][b][j][n208]), 128x128 ----
    {
        BP p{};
        p.A[0] = EAh; p.B[0] = Wkh; p.C[0] = KT;
        p.Mlim[0] = 3136; p.Nlim[0] = 960; p.Klim[0] = 960; p.nKt[0] = 30;
        p.lda[0] = 960; p.ldb[0] = 960; p.ldc[0] = 208;
        p.divA[0] = 1; p.sAhi[0] = 0; p.sAlo[0] = 0;
        p.divB[0] = 1; p.sBhi[0] = 921600; p.sBlo[0] = 0;
        p.divC[0] = 1; p.sChi[0] = 3194880; p.sClo[0] = 0;
        p.tStrB[0] = 199680; p.tComp[0] = 1; p.alpha[0] = 1.0f;
        p.mT[0] = 25; p.nT[0] = 8;
        p.cumEnd[0] = p.cumEnd[1] = p.cumEnd[2] = 800;
        p.totW = 800;
        gemm_w<2><<<800, 256, 0, stream>>>(p);
    }
    // ---- V projection (normal -> Vh[h][3136][960]), 128x128 ----
    {
        BP p{};
        p.A[0] = EAh; p.B[0] = Wvh; p.C[0] = Vh;
        p.Mlim[0] = 3136; p.Nlim[0] = 960; p.Klim[0] = 960; p.nKt[0] = 30;
        p.lda[0] = 960; p.ldb[0] = 960; p.ldc[0] = 960;
        p.divA[0] = 1; p.sAhi[0] = 0; p.sAlo[0] = 0;
        p.divB[0] = 1; p.sBhi[0] = 921600; p.sBlo[0] = 0;
        p.divC[0] = 1; p.sChi[0] = 3010560; p.sClo[0] = 0;
        p.alpha[0] = 1.0f;
        p.mT[0] = 25; p.nT[0] = 8;
        p.cumEnd[0] = p.cumEnd[1] = p.cumEnd[2] = 800;
        p.totW = 800;
        gemm_w<1><<<800, 256, 0, stream>>>(p);
    }

    // ---- Q-proj, all scales: QtT[z][d][n208] (transpose, 64x64) ----
    {
        BP p{};
        int cum = 0;
        for (int s = 0; s < 4; ++s) {
            const int ch = chs[s];
            p.A[s] = Eh + offE[s]; p.B[s] = Wqh + offQ[s]; p.C[s] = QtT + offQt[s];
            p.Mlim[s] = 196; p.Nlim[s] = ch; p.Klim[s] = ch; p.nKt[s] = ch / 32;
            p.lda[s] = ch; p.ldb[s] = ch; p.ldc[s] = 208;
            p.divA[s] = 4; p.sAhi[s] = 196LL * ch; p.sAlo[s] = 0;
            p.divB[s] = 4; p.sBhi[s] = 0; p.sBlo[s] = (long long)ch * ch;
            p.divC[s] = 1; p.sChi[s] = 208LL * ch; p.sClo[s] = 0;
            p.tStrB[s] = 0; p.tComp[s] = 0; p.alpha[s] = 1.0f;
            p.mT[s] = 4; p.nT[s] = ch / 64;
            cum += 4 * (ch / 64) * 64;
            if (s < 3) p.cumEnd[s] = cum;
        }
        p.totW = 3840;
        gemm_b<2><<<3840, 128, 0, stream>>>(p);
    }

    // ---- Scores (raw) + stats, strip-resident ----
    {
        ScP p{};
        for (int s = 0; s < 4; ++s) {
            p.Qt[s] = QtT + offQt[s];
            p.C[s] = Sch + offSc[s];
            p.Part[s] = Part + (long long)s * 64 * 240;
            p.Mlim[s] = chs[s];
            p.sA[s] = 208LL * chs[s];
            p.sC[s] = 960LL * chs[s];
        }
        p.KT = KT;
        p.alpha = inv_sqrt_kv;
        gemm_s<<<512, 256, 0, stream>>>(p);
    }

    // ---- ctx: fused exp/softmax + PV ----
    {
        CtxP p{};
        p.V = Vh;
        const int nP[4] = {1, 1, 2, 4};
        for (int s = 0; s < 4; ++s) {
            p.S[s] = Sch + offSc[s];
            p.C[s] = Ctx + offCtx[s];
            p.Part[s] = Part + (long long)s * 64 * 240;
            p.ch[s] = chs[s];
            p.nPart[s] = nP[s];
            p.pinv[s] = 1.0f / (chs[s] * 960);
        }
        ctx_k<<<1024, 256, 0, stream>>>(p);
    }

    // ---- out-proj, all scales: out fp32 = Ctx (196 x 4ch) x Wo4^T (64x64) ----
    {
        BP p{};
        int cum = 0;
        for (int s = 0; s < 4; ++s) {
            const int ch = chs[s];
            p.A[s] = Ctx + offCtx[s]; p.B[s] = Wo4 + offQ[s]; p.C[s] = out + ooff[s];
            p.Mlim[s] = 196; p.Nlim[s] = ch; p.Klim[s] = 4 * ch; p.nKt[s] = ch / 8;
            p.lda[s] = 4 * ch; p.ldb[s] = 4 * ch; p.ldc[s] = ch;
            p.divA[s] = 1; p.sAhi[s] = 784LL * ch; p.sAlo[s] = 0;
            p.divB[s] = 1; p.sBhi[s] = 0; p.sBlo[s] = 0;
            p.divC[s] = 1; p.sChi[s] = 196LL * ch; p.sClo[s] = 0;
            p.tStrB[s] = 0; p.tComp[s] = 0; p.alpha[s] = 1.0f;
            p.mT[s] = 4; p.nT[s] = ch / 64;
            cum += 4 * (ch / 64) * 16;
            if (s < 3) p.cumEnd[s] = cum;
        }
        p.totW = 960;
        gemm_b<0><<<960, 128, 0, stream>>>(p);
    }
}

// Round 8
// 432.075 us; speedup vs baseline: 6.0691x; 1.0478x over previous
//
#include <hip/hip_runtime.h>

typedef _Float16 half_t;
typedef _Float16 h8 __attribute__((ext_vector_type(8)));
typedef _Float16 h4 __attribute__((ext_vector_type(4)));
typedef float f4v __attribute__((ext_vector_type(4)));

__device__ __forceinline__ int div196(int m) { return (m * 21400) >> 22; }  // exact for m<=3135

// ---------------- prep: cast fp32->fp16 (mode 0) or cast+replicate-4 (mode 1) ----------------
struct PrepArgs {
    const float* src[15];
    half_t* dst[15];
    int n[15];
    int mode[15];
    int lg2[15];
};

__global__ __launch_bounds__(256) void prep_k(PrepArgs a)
{
    const int seg = blockIdx.y;
    const int i8 = (blockIdx.x * 256 + threadIdx.x) * 8;
    if (i8 >= a.n[seg]) return;
    const float* s = a.src[seg] + i8;
    f4v v0 = *(const f4v*)s;
    f4v v1 = *(const f4v*)(s + 4);
    h8 o;
    o[0] = (half_t)v0[0]; o[1] = (half_t)v0[1]; o[2] = (half_t)v0[2]; o[3] = (half_t)v0[3];
    o[4] = (half_t)v1[0]; o[5] = (half_t)v1[1]; o[6] = (half_t)v1[2]; o[7] = (half_t)v1[3];
    if (a.mode[seg] == 0) {
        *(h8*)(a.dst[seg] + i8) = o;
    } else {
        const int lg = a.lg2[seg], ch = 1 << lg;
        const int e = i8 >> lg, d = i8 & (ch - 1);
        half_t* base = a.dst[seg] + ((long long)e << (lg + 2)) + d;
        #pragma unroll
        for (int r = 0; r < 4; ++r) *(h8*)(base + r * ch) = o;
    }
}

// ---------------- staged tile load with row/k-limit masking ----------------
__device__ __forceinline__ h8 ldtile(const half_t* __restrict__ base, int row, int kb,
                                     int ld, int rowLim, int Klim)
{
    h8 v = {0, 0, 0, 0, 0, 0, 0, 0};
    if (row >= rowLim) return v;
    const half_t* p = base + (long long)row * ld + kb;
    if (kb + 8 <= Klim) return *(const h8*)p;
    #pragma unroll
    for (int e = 0; e < 8; ++e) if (kb + e < Klim) v[e] = p[e];
    return v;
}

// ---------------- batch descriptor, up to 6 heterogeneous jobs ----------------
struct BP {
    const half_t* A[6]; const half_t* B[6]; void* C[6];
    int Mlim[6], Nlim[6], Klim[6], nKt[6], lda[6], ldb[6], ldc[6];
    int divA[6]; long long sAhi[6], sAlo[6];
    int divB[6]; long long sBhi[6], sBlo[6];
    int divC[6]; long long sChi[6], sClo[6];
    long long tStrB[6]; int tComp[6];
    int outMode[6];          // 1 = fp16 normal, 2 = fp16 transposed
    float alpha[6];
    int mT[6], nT[6];
    int cumEnd[5];
    int totW;
};

// ---------------- 64x64 MFMA GEMM (2 waves), fp32 normal out — out-proj ----------------
__global__ __launch_bounds__(128)
void gemm_b(BP P)
{
    __shared__ __align__(16) half_t SM[64 * 72];
    half_t (*As)[32] = (half_t(*)[32])SM;
    half_t (*Bs)[32] = (half_t(*)[32])(SM + 2048);

    int b = blockIdx.x;
    int s = 0, basev = 0;
    #pragma unroll
    for (int i = 0; i < 5; ++i) if (b >= P.cumEnd[i]) { s = i + 1; basev = P.cumEnd[i]; }
    b -= basev;
    const int mTl = P.mT[s], nTl = P.nT[s];
    const int mt = b % mTl;
    const int t2 = b / mTl;
    const int nt = t2 % nTl;
    const int z  = t2 / nTl;

    const half_t* A  = P.A[s] + (long long)(z / P.divA[s]) * P.sAhi[s] + (long long)(z % P.divA[s]) * P.sAlo[s];
    const half_t* Bp = P.B[s] + (long long)(z / P.divB[s]) * P.sBhi[s] + (long long)(z % P.divB[s]) * P.sBlo[s];
    const int Mlim = P.Mlim[s], Klim = P.Klim[s], nKt = P.nKt[s];
    const int lda = P.lda[s], ldb = P.ldb[s], ldc = P.ldc[s];
    const float alpha = P.alpha[s];
    const int m0 = mt * 64, n0 = nt * 64;
    const int tid = threadIdx.x;
    const int lane = tid & 63, w = tid >> 6;
    const int l15 = lane & 15, q = lane >> 4;

    const int r0 = tid >> 2, kg = tid & 3;
    const int r1 = r0 + 32;

    f4v acc[4][2];
    #pragma unroll
    for (int i = 0; i < 4; ++i)
        #pragma unroll
        for (int j = 0; j < 2; ++j) acc[i][j] = (f4v){0.f, 0.f, 0.f, 0.f};

    for (int kt = 0; kt < nKt; ++kt) {
        const int kb = kt * 32 + kg * 8;
        h8 a0 = ldtile(A, m0 + r0, kb, lda, Mlim, Klim);
        h8 a1 = ldtile(A, m0 + r1, kb, lda, Mlim, Klim);
        h8 b0 = ldtile(Bp, n0 + r0, kb, ldb, 1 << 30, Klim);
        h8 b1 = ldtile(Bp, n0 + r1, kb, ldb, 1 << 30, Klim);
        __syncthreads();
        *(h8*)&As[r0][kg * 8] = a0;
        *(h8*)&As[r1][kg * 8] = a1;
        *(h8*)&Bs[r0][kg * 8] = b0;
        *(h8*)&Bs[r1][kg * 8] = b1;
        __syncthreads();
        h8 af[4], bf[2];
        #pragma unroll
        for (int mti = 0; mti < 4; ++mti) af[mti] = *(h8*)&As[mti * 16 + l15][q * 8];
        #pragma unroll
        for (int nti = 0; nti < 2; ++nti) bf[nti] = *(h8*)&Bs[w * 32 + nti * 16 + l15][q * 8];
        #pragma unroll
        for (int mti = 0; mti < 4; ++mti)
            #pragma unroll
            for (int nti = 0; nti < 2; ++nti)
                acc[mti][nti] = __builtin_amdgcn_mfma_f32_16x16x32_f16(af[mti], bf[nti], acc[mti][nti], 0, 0, 0);
    }

    float* Cz = (float*)P.C[s] + (long long)(z / P.divC[s]) * P.sChi[s] + (long long)(z % P.divC[s]) * P.sClo[s];
    #pragma unroll
    for (int mti = 0; mti < 4; ++mti)
        #pragma unroll
        for (int r = 0; r < 4; ++r) {
            const int row = m0 + mti * 16 + q * 4 + r;
            if (row < Mlim) {
                #pragma unroll
                for (int nti = 0; nti < 2; ++nti) {
                    const int col = n0 + w * 32 + nti * 16 + l15;
                    Cz[(long long)row * ldc + col] = acc[mti][nti][r] * alpha;
                }
            }
        }
}

// ---------------- 128x128 MFMA GEMM (256 threads) — K/V/Q projections in ONE launch ----------------
// outMode 1 = fp16 normal; 2 = fp16 transposed (C[n][m]); tComp row-splits m over 196.
__global__ __launch_bounds__(256)
void gemm_w(BP P)
{
    __shared__ __align__(16) half_t SMEM[128 * 80];     // As[128][40] + Bs[128][40]; Tt overlay
    half_t (*As)[40] = (half_t(*)[40])SMEM;
    half_t (*Bs)[40] = (half_t(*)[40])(SMEM + 128 * 40);

    const int per = gridDim.x >> 3;
    int wk = (blockIdx.x & 7) * per + (blockIdx.x >> 3);
    if (wk >= P.totW) return;
    int s = 0, basev = 0;
    #pragma unroll
    for (int i = 0; i < 5; ++i) if (wk >= P.cumEnd[i]) { s = i + 1; basev = P.cumEnd[i]; }
    wk -= basev;
    const int mTl = P.mT[s], nTl = P.nT[s];
    const int mt = wk % mTl;
    const int t2 = wk / mTl;
    const int nt = t2 % nTl;
    const int z  = t2 / nTl;

    const half_t* A  = P.A[s] + (long long)(z / P.divA[s]) * P.sAhi[s] + (long long)(z % P.divA[s]) * P.sAlo[s];
    const half_t* Bp = P.B[s] + (long long)(z / P.divB[s]) * P.sBhi[s] + (long long)(z % P.divB[s]) * P.sBlo[s];
    const int Mlim = P.Mlim[s], Nlim = P.Nlim[s], Klim = P.Klim[s], nKt = P.nKt[s];
    const int lda = P.lda[s], ldb = P.ldb[s], ldc = P.ldc[s];
    const float alpha = P.alpha[s];
    const int m0 = mt * 128, n0 = nt * 128;
    const int tid = threadIdx.x;
    const int lane = tid & 63, wv = tid >> 6;
    const int wm = wv & 1, wn = wv >> 1;
    const int l15 = lane & 15, q = lane >> 4;

    const int r0 = tid >> 2, kg = tid & 3;

    f4v acc[4][4];
    #pragma unroll
    for (int i = 0; i < 4; ++i)
        #pragma unroll
        for (int j = 0; j < 4; ++j) acc[i][j] = (f4v){0.f, 0.f, 0.f, 0.f};

    for (int kt = 0; kt < nKt; ++kt) {
        const int kb = kt * 32 + kg * 8;
        h8 a0 = ldtile(A, m0 + r0, kb, lda, Mlim, Klim);
        h8 a1 = ldtile(A, m0 + r0 + 64, kb, lda, Mlim, Klim);
        h8 b0 = ldtile(Bp, n0 + r0, kb, ldb, Nlim, Klim);
        h8 b1 = ldtile(Bp, n0 + r0 + 64, kb, ldb, Nlim, Klim);
        __syncthreads();
        *(h8*)&As[r0][kg * 8] = a0;
        *(h8*)&As[r0 + 64][kg * 8] = a1;
        *(h8*)&Bs[r0][kg * 8] = b0;
        *(h8*)&Bs[r0 + 64][kg * 8] = b1;
        __syncthreads();
        h8 af[4], bf[4];
        #pragma unroll
        for (int mi = 0; mi < 4; ++mi) af[mi] = *(h8*)&As[wm * 64 + mi * 16 + l15][q * 8];
        #pragma unroll
        for (int ni = 0; ni < 4; ++ni) bf[ni] = *(h8*)&Bs[wn * 64 + ni * 16 + l15][q * 8];
        #pragma unroll
        for (int mi = 0; mi < 4; ++mi)
            #pragma unroll
            for (int ni = 0; ni < 4; ++ni)
                acc[mi][ni] = __builtin_amdgcn_mfma_f32_16x16x32_f16(af[mi], bf[ni], acc[mi][ni], 0, 0, 0);
    }

    if (P.outMode[s] == 1) {
        half_t* Cz = (half_t*)P.C[s] + (long long)(z / P.divC[s]) * P.sChi[s] + (long long)(z % P.divC[s]) * P.sClo[s];
        #pragma unroll
        for (int mi = 0; mi < 4; ++mi)
            #pragma unroll
            for (int r = 0; r < 4; ++r) {
                const int row = m0 + wm * 64 + mi * 16 + q * 4 + r;
                if (row < Mlim) {
                    #pragma unroll
                    for (int ni = 0; ni < 4; ++ni) {
                        const int col = n0 + wn * 64 + ni * 16 + l15;
                        if (col < Nlim) Cz[(long long)row * ldc + col] = (half_t)(acc[mi][ni][r] * alpha);
                    }
                }
            }
    } else {
        // transpose epilogue, two half-passes through LDS overlay.
        // rows mg >= Mlim must NOT be written (div196 of OOB row walks into next plane).
        half_t (*Tt)[72] = (half_t(*)[72])SMEM;   // 128 x 72 halves <= SMEM
        half_t* Cz = (half_t*)P.C[s] + (long long)(z / P.divC[s]) * P.sChi[s] + (long long)(z % P.divC[s]) * P.sClo[s];
        const long long tStrB = P.tStrB[s];
        const int jl = tid >> 1, mh = (tid & 1) * 32;
        #pragma unroll
        for (int p = 0; p < 2; ++p) {
            __syncthreads();
            if (wm == p) {
                #pragma unroll
                for (int mi = 0; mi < 4; ++mi)
                    #pragma unroll
                    for (int ni = 0; ni < 4; ++ni) {
                        h4 pk;
                        #pragma unroll
                        for (int r = 0; r < 4; ++r) pk[r] = (half_t)(acc[mi][ni][r] * alpha);
                        *(h4*)&Tt[wn * 64 + ni * 16 + l15][mi * 16 + q * 4] = pk;
                    }
            }
            __syncthreads();
            const int n = n0 + jl;
            if (n < Nlim) {
                #pragma unroll
                for (int g = 0; g < 4; ++g) {
                    const int ml = mh + g * 8;
                    const int mg = m0 + p * 64 + ml;
                    h8 v = *(h8*)&Tt[jl][ml];
                    if (P.tComp[s]) {
                        const int b0 = div196(mg), b1 = div196(mg + 7);
                        if (b0 == b1 && mg + 8 <= Mlim) {
                            half_t* rp = Cz + (long long)b0 * tStrB + (long long)n * ldc + (mg - 196 * b0);
                            h4 lo = {v[0], v[1], v[2], v[3]};
                            h4 hi = {v[4], v[5], v[6], v[7]};
                            *(h4*)rp = lo;
                            *(h4*)(rp + 4) = hi;
                        } else {
                            #pragma unroll
                            for (int e = 0; e < 8; ++e) {
                                const int m = mg + e;
                                if (m < Mlim) {
                                    const int bb = div196(m);
                                    Cz[(long long)bb * tStrB + (long long)n * ldc + (m - 196 * bb)] = v[e];
                                }
                            }
                        }
                    } else {
                        if (mg + 8 <= Mlim) {
                            *(h8*)(Cz + (long long)n * ldc + mg) = v;
                        } else {
                            #pragma unroll
                            for (int e = 0; e < 8; ++e)
                                if (mg + e < Mlim) Cz[(long long)n * ldc + mg + e] = v[e];
                        }
                    }
                }
            }
        }
    }
}

// ---------------- scores: A-strip-resident GEMM + fused IN-stat partials ----------------
struct ScP {
    const half_t* Qt[4];
    const half_t* KT;
    half_t* C[4];
    float* Part[4];
    int Mlim[4];
    long long sA[4], sC[4];
    float alpha;
};

__global__ __launch_bounds__(256)
void gemm_s(ScP P)
{
    __shared__ __align__(16) half_t As[128][232];   // full-K strip (196 -> zero-pad)
    __shared__ __align__(16) half_t Bs[128][72];    // 64-wide B chunk
    __shared__ float red[8];

    const int per = gridDim.x >> 3;                 // 512/8 = 64 -> 8 z per XCD
    int wk = (blockIdx.x & 7) * per + (blockIdx.x >> 3);
    const int z = wk >> 3, r = wk & 7;
    int s, mt;
    if (r < 1)      { s = 0; mt = 0; }
    else if (r < 2) { s = 1; mt = 0; }
    else if (r < 4) { s = 2; mt = r - 2; }
    else            { s = 3; mt = r - 4; }
    const int b = z >> 2, h = z & 3;

    const half_t* A = P.Qt[s] + (long long)z * P.sA[s] + (long long)mt * 128 * 208;
    const half_t* B = P.KT + (long long)h * 3194880 + (long long)b * 199680;
    const int rowLim = P.Mlim[s] - mt * 128;
    const float alpha = P.alpha;

    const int tid = threadIdx.x;
    const int lane = tid & 63, wv = tid >> 6;
    const int wm = wv & 1, wn = wv >> 1;
    const int l15 = lane & 15, q = lane >> 4;
    const int r0 = tid >> 2, kg = tid & 3;

    #pragma unroll
    for (int c = 0; c < 7; ++c) {
        const int kb = c * 32 + kg * 8;
        h8 a0 = ldtile(A, r0, kb, 208, rowLim, 196);
        h8 a1 = ldtile(A, r0 + 64, kb, 208, rowLim, 196);
        *(h8*)&As[r0][kb] = a0;
        *(h8*)&As[r0 + 64][kb] = a1;
    }

    half_t* Cz = P.C[s] + (long long)z * P.sC[s] + (long long)mt * 128 * 960;
    float sv = 0.f, qq = 0.f;

    for (int nt = 0; nt < 8; ++nt) {
        f4v acc[4][4];
        #pragma unroll
        for (int i = 0; i < 4; ++i)
            #pragma unroll
            for (int j = 0; j < 4; ++j) acc[i][j] = (f4v){0.f, 0.f, 0.f, 0.f};

        const int j0 = nt * 128;
        #pragma unroll
        for (int c2 = 0; c2 < 4; ++c2) {
            h8 b00 = ldtile(B, j0 + r0,      c2 * 64 + kg * 8,      208, 960, 196);
            h8 b01 = ldtile(B, j0 + r0,      c2 * 64 + 32 + kg * 8, 208, 960, 196);
            h8 b10 = ldtile(B, j0 + r0 + 64, c2 * 64 + kg * 8,      208, 960, 196);
            h8 b11 = ldtile(B, j0 + r0 + 64, c2 * 64 + 32 + kg * 8, 208, 960, 196);
            __syncthreads();
            *(h8*)&Bs[r0][kg * 8] = b00;
            *(h8*)&Bs[r0][32 + kg * 8] = b01;
            *(h8*)&Bs[r0 + 64][kg * 8] = b10;
            *(h8*)&Bs[r0 + 64][32 + kg * 8] = b11;
            __syncthreads();
            const int nkk = (c2 < 3) ? 2 : 1;
            for (int kk = 0; kk < nkk; ++kk) {
                const int base = c2 * 64 + kk * 32;
                h8 af[4], bf[4];
                #pragma unroll
                for (int mi = 0; mi < 4; ++mi) af[mi] = *(h8*)&As[wm * 64 + mi * 16 + l15][base + q * 8];
                #pragma unroll
                for (int ni = 0; ni < 4; ++ni) bf[ni] = *(h8*)&Bs[wn * 64 + ni * 16 + l15][kk * 32 + q * 8];
                #pragma unroll
                for (int mi = 0; mi < 4; ++mi)
                    #pragma unroll
                    for (int ni = 0; ni < 4; ++ni)
                        acc[mi][ni] = __builtin_amdgcn_mfma_f32_16x16x32_f16(af[mi], bf[ni], acc[mi][ni], 0, 0, 0);
            }
        }
        #pragma unroll
        for (int mi = 0; mi < 4; ++mi)
            #pragma unroll
            for (int rr = 0; rr < 4; ++rr) {
                const int rowl = wm * 64 + mi * 16 + q * 4 + rr;
                #pragma unroll
                for (int ni = 0; ni < 4; ++ni) {
                    const int col = j0 + wn * 64 + ni * 16 + l15;
                    const float v = acc[mi][ni][rr] * alpha;
                    sv += v; qq += v * v;
                    if (rowl < rowLim && col < 960)
                        Cz[(long long)rowl * 960 + col] = (half_t)v;
                }
            }
    }

    #pragma unroll
    for (int o = 32; o > 0; o >>= 1) {
        sv += __shfl_down(sv, o, 64);
        qq += __shfl_down(qq, o, 64);
    }
    if (lane == 0) { red[wv] = sv; red[4 + wv] = qq; }
    __syncthreads();
    if (tid == 0) {
        float* PO = P.Part[s] + (long long)z * 240 + mt * 2;
        PO[0] = red[0] + red[1] + red[2] + red[3];
        PO[1] = red[4] + red[5] + red[6] + red[7];
    }
}

// ---------------- ctx: fused IN-scale + exp + PV GEMM + denominator normalize ----------------
// SOFTWARE-PIPELINED: loads for iter k+1 issue before MFMA of iter k; exp(k) computed
// at top of iter k from last iteration's loads (off the load-latency critical path).
struct CtxP {
    const half_t* V;
    const half_t* S[4];
    half_t* C[4];
    const float* Part[4];
    int ch[4];
    int nPart[4];
    float pinv[4];
};

__global__ __launch_bounds__(256)
void ctx_k(CtxP P)
{
    __shared__ __align__(16) half_t As[128][40];
    __shared__ __align__(16) half_t Bs[128][40];
    __shared__ float denomP[128][4];
    __shared__ float denom[128];

    const int per = gridDim.x >> 3;                 // 1024/8 = 128 -> 8 z per XCD
    int wk = (blockIdx.x & 7) * per + (blockIdx.x >> 3);
    const int z = wk >> 4;
    const int r = wk & 15;
    int s, mt, nt;
    if (r < 2)      { s = 0; mt = r;            nt = 0; }
    else if (r < 4) { s = 1; mt = r - 2;        nt = 0; }
    else if (r < 8) { s = 2; mt = (r - 4) >> 1; nt = (r - 4) & 1; }
    else            { s = 3; mt = (r - 8) >> 2; nt = (r - 8) & 3; }
    const int b = z >> 2, h = z & 3;
    const int chS = P.ch[s];

    const float* part = P.Part[s] + (long long)z * 240;
    float Ssum = 0.f, Qsum = 0.f;
    for (int i = 0; i < P.nPart[s]; ++i) { Ssum += part[i * 2]; Qsum += part[i * 2 + 1]; }
    const float mn = Ssum * P.pinv[s];
    const float rs = rsqrtf(fmaxf(Qsum * P.pinv[s] - mn * mn, 0.f) + 1e-5f);

    const half_t* Av  = P.V + (long long)h * 3010560 + (long long)b * 188160;   // [196][960]
    const half_t* Bsc = P.S[s] + (long long)z * 960 * chS;                      // [ch][960] raw
    const int m0 = mt * 128, n0 = nt * 128;

    const int tid = threadIdx.x;
    const int lane = tid & 63, wv = tid >> 6;
    const int wm = wv & 1, wn = wv >> 1;
    const int l15 = lane & 15, q = lane >> 4;
    const int r0 = tid >> 2, kg = tid & 3;
    const int d0 = n0 + r0, d1 = n0 + r0 + 64;
    const bool ok0 = d0 < chS, ok1 = d1 < chS;

    f4v acc[4][4];
    #pragma unroll
    for (int i = 0; i < 4; ++i)
        #pragma unroll
        for (int j = 0; j < 4; ++j) acc[i][j] = (f4v){0.f, 0.f, 0.f, 0.f};

    float ds0 = 0.f, ds1 = 0.f;

    // prologue: loads for kt=0
    h8 a0n = ldtile(Av, m0 + r0, kg * 8, 960, 196, 960);
    h8 a1n = ldtile(Av, m0 + r0 + 64, kg * 8, 960, 196, 960);
    h8 s0n = {0,0,0,0,0,0,0,0}, s1n = {0,0,0,0,0,0,0,0};
    if (ok0) s0n = *(const h8*)(Bsc + (long long)d0 * 960 + kg * 8);
    if (ok1) s1n = *(const h8*)(Bsc + (long long)d1 * 960 + kg * 8);

    for (int kt = 0; kt < 30; ++kt) {
        // exp of current iteration's scores (loads completed during previous MFMA)
        h8 e0 = {0,0,0,0,0,0,0,0}, e1 = {0,0,0,0,0,0,0,0};
        if (ok0) {
            #pragma unroll
            for (int e = 0; e < 8; ++e) { float ev = __expf((float)s0n[e] * rs); ds0 += ev; e0[e] = (half_t)ev; }
        }
        if (ok1) {
            #pragma unroll
            for (int e = 0; e < 8; ++e) { float ev = __expf((float)s1n[e] * rs); ds1 += ev; e1[e] = (half_t)ev; }
        }
        h8 a0c = a0n, a1c = a1n;
        __syncthreads();
        *(h8*)&As[r0][kg * 8] = a0c;
        *(h8*)&As[r0 + 64][kg * 8] = a1c;
        *(h8*)&Bs[r0][kg * 8] = e0;
        *(h8*)&Bs[r0 + 64][kg * 8] = e1;
        __syncthreads();
        if (kt < 29) {
            const int kb = (kt + 1) * 32 + kg * 8;
            a0n = ldtile(Av, m0 + r0, kb, 960, 196, 960);
            a1n = ldtile(Av, m0 + r0 + 64, kb, 960, 196, 960);
            if (ok0) s0n = *(const h8*)(Bsc + (long long)d0 * 960 + kb);
            if (ok1) s1n = *(const h8*)(Bsc + (long long)d1 * 960 + kb);
        }
        h8 af[4], bf[4];
        #pragma unroll
        for (int mi = 0; mi < 4; ++mi) af[mi] = *(h8*)&As[wm * 64 + mi * 16 + l15][q * 8];
        #pragma unroll
        for (int ni = 0; ni < 4; ++ni) bf[ni] = *(h8*)&Bs[wn * 64 + ni * 16 + l15][q * 8];
        #pragma unroll
        for (int mi = 0; mi < 4; ++mi)
            #pragma unroll
            for (int ni = 0; ni < 4; ++ni)
                acc[mi][ni] = __builtin_amdgcn_mfma_f32_16x16x32_f16(af[mi], bf[ni], acc[mi][ni], 0, 0, 0);
    }

    denomP[r0][kg] = ds0;
    denomP[r0 + 64][kg] = ds1;
    __syncthreads();
    if (tid < 128) denom[tid] = denomP[tid][0] + denomP[tid][1] + denomP[tid][2] + denomP[tid][3];
    __syncthreads();

    half_t* Cz = P.C[s] + (long long)b * 784 * chS + (long long)h * chS;
    const int ldc = 4 * chS;
    #pragma unroll
    for (int ni = 0; ni < 4; ++ni) {
        const int coll = wn * 64 + ni * 16 + l15;
        const int col = n0 + coll;
        if (col < chS) {
            const float sc = 0.25f / denom[coll];
            #pragma unroll
            for (int mi = 0; mi < 4; ++mi)
                #pragma unroll
                for (int rr = 0; rr < 4; ++rr) {
                    const int row = m0 + wm * 64 + mi * 16 + q * 4 + rr;
                    if (row < 196)
                        Cz[(long long)row * ldc + col] = (half_t)(acc[mi][ni][rr] * sc);
                }
        }
    }
}

// ---------------- launcher ----------------
extern "C" void kernel_launch(void* const* d_in, const int* in_sizes, int n_in,
                              void* d_out, int out_size, void* d_ws, size_t ws_size,
                              hipStream_t stream)
{
    const float* emb[4]  = {(const float*)d_in[0], (const float*)d_in[1],
                            (const float*)d_in[2], (const float*)d_in[3]};
    const float* emb_all = (const float*)d_in[4];
    const float* Wq[4]   = {(const float*)d_in[5], (const float*)d_in[7],
                            (const float*)d_in[9], (const float*)d_in[11]};
    const float* Wo[4]   = {(const float*)d_in[6], (const float*)d_in[8],
                            (const float*)d_in[10], (const float*)d_in[12]};
    const float* Wk = (const float*)d_in[13];
    const float* Wv = (const float*)d_in[14];
    float* out = (float*)d_out;

    half_t* hb = (half_t*)d_ws;
    half_t* EAh = hb;                              // 3010560
    half_t* Eh  = EAh + 3010560;                   // 3010560
    half_t* Wkh = Eh  + 3010560;                   // 3686400
    half_t* Wvh = Wkh + 3686400;                   // 3686400
    half_t* Wqh = Wvh + 3686400;                   // 1392640
    half_t* Wo4 = Wqh + 1392640;                   // 1392640
    half_t* KT  = Wo4 + 1392640;                   // [h][b][960][208]      = 12779520
    half_t* Vh  = KT  + 12779520;                  // [h][3136][960]        = 12042240
    half_t* QtT = Vh  + 12042240;                  // per-scale [64][ch][208] = 12779520
    half_t* Ctx = QtT + 12779520;                  // per-scale [16][196][4ch] = 12042240
    half_t* Sch = Ctx + 12042240;                  // per-scale [64][ch][960] raw = 58982400
    float*  Part = (float*)(Sch + 58982400);       // 4 * 64 * 240 floats

    const int  chs[4]   = {64, 128, 256, 512};
    const int  lg2c[4]  = {6, 7, 8, 9};
    const long long offE[4]   = {0, 200704, 602112, 1404928};
    const long long offQ[4]   = {0, 16384, 81920, 344064};
    const long long offQt[4]  = {0, 851968, 2555904, 5963776};
    const long long offSc[4]  = {0, 3932160, 11796480, 27525120};
    const long long offCtx[4] = {0, 802816, 2408448, 5619712};
    const long long ooff[4]   = {0, 200704, 602112, 1404928};
    const float inv_sqrt_kv = 0.03227486121839514f;

    // ---- prep ----
    PrepArgs pa;
    pa.src[0] = emb_all; pa.dst[0] = EAh; pa.n[0] = 3010560; pa.mode[0] = 0; pa.lg2[0] = 0;
    for (int i = 0; i < 4; ++i) {
        pa.src[1 + i] = emb[i]; pa.dst[1 + i] = Eh + offE[i];
        pa.n[1 + i] = (int)(3136LL * chs[i]); pa.mode[1 + i] = 0; pa.lg2[1 + i] = 0;
    }
    pa.src[5] = Wk; pa.dst[5] = Wkh; pa.n[5] = 3686400; pa.mode[5] = 0; pa.lg2[5] = 0;
    pa.src[6] = Wv; pa.dst[6] = Wvh; pa.n[6] = 3686400; pa.mode[6] = 0; pa.lg2[6] = 0;
    for (int i = 0; i < 4; ++i) {
        pa.src[7 + i] = Wq[i]; pa.dst[7 + i] = Wqh + offQ[i];
        pa.n[7 + i] = 4 * chs[i] * chs[i]; pa.mode[7 + i] = 0; pa.lg2[7 + i] = 0;
        pa.src[11 + i] = Wo[i]; pa.dst[11 + i] = Wo4 + offQ[i];
        pa.n[11 + i] = chs[i] * chs[i]; pa.mode[11 + i] = 1; pa.lg2[11 + i] = lg2c[i];
    }
    prep_k<<<dim3(1800, 15), 256, 0, stream>>>(pa);

    // ---- K-proj + V-proj + Q-proj (all scales) in ONE 128x128 launch ----
    {
        BP p{};
        // slot 0: K projection -> KT[h][b][j][n208] (transposed, row-split over 196)
        p.A[0] = EAh; p.B[0] = Wkh; p.C[0] = KT;
        p.Mlim[0] = 3136; p.Nlim[0] = 960; p.Klim[0] = 960; p.nKt[0] = 30;
        p.lda[0] = 960; p.ldb[0] = 960; p.ldc[0] = 208;
        p.divA[0] = 1; p.sAhi[0] = 0; p.sAlo[0] = 0;
        p.divB[0] = 1; p.sBhi[0] = 921600; p.sBlo[0] = 0;
        p.divC[0] = 1; p.sChi[0] = 3194880; p.sClo[0] = 0;
        p.tStrB[0] = 199680; p.tComp[0] = 1; p.outMode[0] = 2; p.alpha[0] = 1.0f;
        p.mT[0] = 25; p.nT[0] = 8;
        // slot 1: V projection -> Vh[h][3136][960] (normal)
        p.A[1] = EAh; p.B[1] = Wvh; p.C[1] = Vh;
        p.Mlim[1] = 3136; p.Nlim[1] = 960; p.Klim[1] = 960; p.nKt[1] = 30;
        p.lda[1] = 960; p.ldb[1] = 960; p.ldc[1] = 960;
        p.divA[1] = 1; p.sAhi[1] = 0; p.sAlo[1] = 0;
        p.divB[1] = 1; p.sBhi[1] = 921600; p.sBlo[1] = 0;
        p.divC[1] = 1; p.sChi[1] = 3010560; p.sClo[1] = 0;
        p.tStrB[1] = 0; p.tComp[1] = 0; p.outMode[1] = 1; p.alpha[1] = 1.0f;
        p.mT[1] = 25; p.nT[1] = 8;
        // slots 2..5: Q-proj per scale -> QtT[z][d][n208] (transposed, no row-split)
        for (int i = 0; i < 4; ++i) {
            const int sl = 2 + i, ch = chs[i];
            p.A[sl] = Eh + offE[i]; p.B[sl] = Wqh + offQ[i]; p.C[sl] = QtT + offQt[i];
            p.Mlim[sl] = 196; p.Nlim[sl] = ch; p.Klim[sl] = ch; p.nKt[sl] = ch / 32;
            p.lda[sl] = ch; p.ldb[sl] = ch; p.ldc[sl] = 208;
            p.divA[sl] = 4; p.sAhi[sl] = 196LL * ch; p.sAlo[sl] = 0;
            p.divB[sl] = 4; p.sBhi[sl] = 0; p.sBlo[sl] = (long long)ch * ch;
            p.divC[sl] = 1; p.sChi[sl] = 208LL * ch; p.sClo[sl] = 0;
            p.tStrB[sl] = 0; p.tComp[sl] = 0; p.outMode[sl] = 2; p.alpha[sl] = 1.0f;
            p.mT[sl] = 2; p.nT[sl] = (ch + 127) / 128;
        }
        int cum = 0;
        const int blocks[6] = {800, 800, 128, 128, 256, 512};
        for (int sl = 0; sl < 6; ++sl) { cum += blocks[sl]; if (sl < 5) p.cumEnd[sl] = cum; }
        p.totW = cum;                       // 2624, divisible by 8
        gemm_w<<<2624, 256, 0, stream>>>(p);
    }

    // ---- Scores (raw) + stats, strip-resident ----
    {
        ScP p{};
        for (int s = 0; s < 4; ++s) {
            p.Qt[s] = QtT + offQt[s];
            p.C[s] = Sch + offSc[s];
            p.Part[s] = Part + (long long)s * 64 * 240;
            p.Mlim[s] = chs[s];
            p.sA[s] = 208LL * chs[s];
            p.sC[s] = 960LL * chs[s];
        }
        p.KT = KT;
        p.alpha = inv_sqrt_kv;
        gemm_s<<<512, 256, 0, stream>>>(p);
    }

    // ---- ctx: fused exp/softmax + PV (pipelined) ----
    {
        CtxP p{};
        p.V = Vh;
        const int nP[4] = {1, 1, 2, 4};
        for (int s = 0; s < 4; ++s) {
            p.S[s] = Sch + offSc[s];
            p.C[s] = Ctx + offCtx[s];
            p.Part[s] = Part + (long long)s * 64 * 240;
            p.ch[s] = chs[s];
            p.nPart[s] = nP[s];
            p.pinv[s] = 1.0f / (chs[s] * 960);
        }
        ctx_k<<<1024, 256, 0, stream>>>(p);
    }

    // ---- out-proj, all scales: out fp32 = Ctx (196 x 4ch) x Wo4^T (64x64) ----
    {
        BP p{};
        int cum = 0;
        for (int s = 0; s < 4; ++s) {
            const int ch = chs[s];
            p.A[s] = Ctx + offCtx[s]; p.B[s] = Wo4 + offQ[s]; p.C[s] = out + ooff[s];
            p.Mlim[s] = 196; p.Nlim[s] = ch; p.Klim[s] = 4 * ch; p.nKt[s] = ch / 8;
            p.lda[s] = 4 * ch; p.ldb[s] = 4 * ch; p.ldc[s] = ch;
            p.divA[s] = 1; p.sAhi[s] = 784LL * ch; p.sAlo[s] = 0;
            p.divB[s] = 1; p.sBhi[s] = 0; p.sBlo[s] = 0;
            p.divC[s] = 1; p.sChi[s] = 196LL * ch; p.sClo[s] = 0;
            p.tStrB[s] = 0; p.tComp[s] = 0; p.outMode[s] = 0; p.alpha[s] = 1.0f;
            p.mT[s] = 4; p.nT[s] = ch / 64;
            cum += 4 * (ch / 64) * 16;
            if (s < 3) p.cumEnd[s] = cum;
        }
        p.cumEnd[3] = p.cumEnd[4] = cum;
        p.totW = cum;
        gemm_b<<<960, 128, 0, stream>>>(p);
    }
}